// Round 5
// baseline (10428.245 us; speedup 1.0000x reference)
//
#include <hip/hip_runtime.h>
#include <hip/hip_bf16.h>
#include <hip/hip_fp16.h>
#include <cstdint>

// Problem constants
#define BB   64
#define TT   128
#define KK   4
#define LL   128
#define SS   64
#define AA   64
#define DQN  32
#define UU   256
#define NAOUT 164
#define WDIM 300
#define PDIM 64
#define ADIM 64

// ---- Fallback (round-2) full-pack row offsets ----
#define OFF_TREE 0
#define OFF_S0   512
#define OFF_S1   1024
#define OFF_FW0  1536
#define OFF_BW0  2048
#define OFF_FW1  2560
#define OFF_BW1  3328
#define OFF_ACT0 4096
#define OFF_ACT1 4416
#define OFF_DQ0  4928
#define OFF_DQ1  5440
#define PK_ROWS_FB 5952

// ---- Plan-B pack: tree full (512 rows) + h-rows only for the rest ----
#define PKH_FW0  512
#define PKH_BW0  768
#define PKH_FW1  1024
#define PKH_BW1  1280
#define PKH_S0   1536
#define PKH_S1   1792
#define PKH_ACT0 2048
#define PKH_ACT1 2304
#define PKH_DQ0  2560
#define PKH_DQ1  2816
#define PK_ROWS_B 3072

typedef unsigned short ushort_t;
typedef unsigned int   uint_t;

__device__ __forceinline__ float bf2f(ushort_t s) {
    return __uint_as_float(((uint_t)s) << 16);
}
__device__ __forceinline__ ushort_t f2bf(float x) {
    __hip_bfloat16 h = __float2bfloat16(x);
    return *reinterpret_cast<ushort_t*>(&h);
}
__device__ __forceinline__ float sigm(float x) { return 1.0f / (1.0f + expf(-x)); }

__device__ __forceinline__ uint_t pack2h(float a, float b) {
    __half2 h = __floats2half2_rn(a, b);
    return *reinterpret_cast<uint_t*>(&h);
}
__device__ __forceinline__ float2 unp2h(uint_t v) {
    __half2 h = *reinterpret_cast<__half2*>(&v);
    return __half22float2(h);
}

// Dual-dtype load: F32=true -> buffer holds float32; false -> bf16.
template<bool F32>
__device__ __forceinline__ float ld1(const void* p_, size_t i) {
    if constexpr (F32) return reinterpret_cast<const float*>(p_)[i];
    else               return bf2f(reinterpret_cast<const ushort_t*>(p_)[i]);
}

struct P {
    // int inputs
    const int *tree_word_id, *tree_pos_id, *token_word_id, *token_pos_id, *history_action_id,
              *buff_top_id, *deque_word_id, *deque_pos_id, *deque_length, *children_order,
              *stack_order, *stack_length, *token_length, *history_action_length;
    // float-family params (dtype resolved at runtime)
    const void *word_emb, *pos_emb, *act_emb, *wd_W, *wd_b, *tree_W, *tree_b,
        *stack0_W, *stack0_b, *stack1_W, *stack1_b, *fw0_W, *fw0_b, *bw0_W, *bw0_b,
        *fw1_W, *fw1_b, *bw1_W, *bw1_b, *act0_W, *act0_b, *act1_W, *act1_b,
        *dq0_W, *dq0_b, *dq1_W, *dq1_b, *fin_W, *fin_b;
    // workspace
    int* flag;                          // [0]: 0 = bf16 world, 1 = f32 world
    float *stack_h, *fw1_h, *fw_top, *bw_top, *bw_bottom, *act_h, *dq_h;  // f32
    float *tree_e;                      // f32 (tree dynamics chaotic — stays f32 end-to-end)
    ushort_t *token_e, *deque_e, *x1;   // bf16
    float *H, *C;                       // f32
    float *a0_seq, *d0_seq, *s0_seq;    // f32 layer-0 h sequences (plan B)
    // zx buffers: fp16x4 per (n, unit): x-part of gate preactivations incl. bias (+forget bias)
    uint2 *zxA, *zxB, *zxC, *zxD, *zxS;
    // packed weights: float4 {g0,g1,g2,g3} per (row, u)
    float4* pkf;
};

// ---------------------------------------------------------------------------
// dtype detector
// ---------------------------------------------------------------------------
__global__ void detect_kernel(const uint_t* w, int* flag) {
    __shared__ int cnt;
    if (threadIdx.x == 0) cnt = 0;
    __syncthreads();
    int local = 0;
    for (int i = threadIdx.x; i < 256; i += 64) {
        uint_t lo = w[i] & 0xFFFFu;
        uint_t e  = (lo >> 7) & 0xFFu;
        if (lo == 0u || (e >= 0x6Cu && e <= 0x7Fu)) local++;
    }
    atomicAdd(&cnt, local);
    __syncthreads();
    if (threadIdx.x == 0) flag[0] = (cnt >= 200) ? 0 : 1;
}

__global__ void sentinel_kernel(void* out, float v) {
    if (threadIdx.x == 0) {
        reinterpret_cast<float*>(out)[0] = v;
        reinterpret_cast<__hip_bfloat16*>(out)[2] = __float2bfloat16(v);
    }
}

// ---------------------------------------------------------------------------
// Weight packing — fallback (full rows)
// ---------------------------------------------------------------------------
__global__ __launch_bounds__(256) void pack_fb_kernel(P p) {
    const bool f32 = (p.flag[0] == 1);
    const int rg = blockIdx.x;
    const int u  = threadIdx.x;
    const void* src; int r;
    if      (rg < 512)  { src = p.tree_W;   r = rg; }
    else if (rg < 1024) { src = p.stack0_W; r = rg - 512; }
    else if (rg < 1536) { src = p.stack1_W; r = rg - 1024; }
    else if (rg < 2048) { src = p.fw0_W;    r = rg - 1536; }
    else if (rg < 2560) { src = p.bw0_W;    r = rg - 2048; }
    else if (rg < 3328) { src = p.fw1_W;    r = rg - 2560; }
    else if (rg < 4096) { src = p.bw1_W;    r = rg - 3328; }
    else if (rg < 4416) { src = p.act0_W;   r = rg - 4096; }
    else if (rg < 4928) { src = p.act1_W;   r = rg - 4416; }
    else if (rg < 5440) { src = p.dq0_W;    r = rg - 4928; }
    else                { src = p.dq1_W;    r = rg - 5440; }
    const size_t ro = (size_t)r * 1024;
    float4 v;
    if (f32) {
        const float* s = reinterpret_cast<const float*>(src) + ro;
        v = make_float4(s[u], s[256 + u], s[512 + u], s[768 + u]);
    } else {
        const ushort_t* s = reinterpret_cast<const ushort_t*>(src) + ro;
        v = make_float4(bf2f(s[u]), bf2f(s[256 + u]), bf2f(s[512 + u]), bf2f(s[768 + u]));
    }
    p.pkf[(size_t)rg * 256 + u] = v;
}

// ---------------------------------------------------------------------------
// Weight packing — plan B (tree full + h-rows only)
// ---------------------------------------------------------------------------
__global__ __launch_bounds__(256) void pack_h_kernel(P p) {
    const bool f32 = (p.flag[0] == 1);
    const int rg = blockIdx.x;
    const int u  = threadIdx.x;
    const void* src; int r;
    if      (rg < 512)  { src = p.tree_W;   r = rg; }
    else if (rg < 768)  { src = p.fw0_W;    r = 256 + rg - 512; }
    else if (rg < 1024) { src = p.bw0_W;    r = 256 + rg - 768; }
    else if (rg < 1280) { src = p.fw1_W;    r = 512 + rg - 1024; }
    else if (rg < 1536) { src = p.bw1_W;    r = 512 + rg - 1280; }
    else if (rg < 1792) { src = p.stack0_W; r = 256 + rg - 1536; }
    else if (rg < 2048) { src = p.stack1_W; r = 256 + rg - 1792; }
    else if (rg < 2304) { src = p.act0_W;   r = 64  + rg - 2048; }
    else if (rg < 2560) { src = p.act1_W;   r = 256 + rg - 2304; }
    else if (rg < 2816) { src = p.dq0_W;    r = 256 + rg - 2560; }
    else                { src = p.dq1_W;    r = 256 + rg - 2816; }
    const size_t ro = (size_t)r * 1024;
    float4 v;
    if (f32) {
        const float* s = reinterpret_cast<const float*>(src) + ro;
        v = make_float4(s[u], s[256 + u], s[512 + u], s[768 + u]);
    } else {
        const ushort_t* s = reinterpret_cast<const ushort_t*>(src) + ro;
        v = make_float4(bf2f(s[u]), bf2f(s[256 + u]), bf2f(s[512 + u]), bf2f(s[768 + u]));
    }
    p.pkf[(size_t)rg * 256 + u] = v;
}

// ---------------------------------------------------------------------------
// Embedding
// ---------------------------------------------------------------------------
template<bool F32>
__device__ void embed_impl(const P& p, float* s_e) {
    const int u   = threadIdx.x;
    const int row = blockIdx.x;

    const int* wid; const int* pid; int rowbase; int which;
    float* out_f = nullptr; ushort_t* out_b = nullptr;
    if (row < BB * TT) {
        wid = p.tree_word_id; pid = p.tree_pos_id; rowbase = row; which = 0;
        out_f = p.tree_e;
    } else if (row < BB * TT + BB * LL) {
        wid = p.token_word_id; pid = p.token_pos_id; rowbase = row - BB * TT; which = 1;
        out_b = p.token_e;
    } else {
        wid = p.deque_word_id; pid = p.deque_pos_id; rowbase = row - BB * TT - BB * LL; which = 2;
        out_b = p.deque_e;
    }

    const int w  = wid[rowbase];
    const int pp = pid[rowbase];
    for (int e = u; e < WDIM + PDIM; e += 256) {
        s_e[e] = (e < WDIM) ? ld1<F32>(p.word_emb, (size_t)w * WDIM + e)
                            : ld1<F32>(p.pos_emb, (size_t)pp * PDIM + (e - WDIM));
    }
    __syncthreads();

    float acc = ld1<F32>(p.wd_b, u);
    for (int r = 0; r < WDIM + PDIM; ++r)
        acc = fmaf(s_e[r], ld1<F32>(p.wd_W, (size_t)r * UU + u), acc);
    acc = fmaxf(acc, 0.f);
    if (which == 0) out_f[(size_t)rowbase * UU + u] = acc;
    else            out_b[(size_t)rowbase * UU + u] = f2bf(acc);
}

__global__ __launch_bounds__(256) void embed_kernel(P p) {
    __shared__ __align__(16) float s_e[384];
    if (p.flag[0] == 1) embed_impl<true>(p, s_e);
    else                embed_impl<false>(p, s_e);
}

// ---------------------------------------------------------------------------
// One LSTM step over packed float4 weights (256-thread fallback version).
// ---------------------------------------------------------------------------
template<int R>
__device__ __forceinline__ float lstm_step_f4(const float4* __restrict__ Wp,
                                              const float4 bz,
                                              const float* __restrict__ s_xh,
                                              float& c) {
    float zi = bz.x, zj = bz.y, zf = bz.z, zo = bz.w;
    for (int r0 = 0; r0 < R; r0 += 16) {
        float4 w[16];
        #pragma unroll
        for (int k = 0; k < 16; ++k) w[k] = Wp[(size_t)(r0 + k) * 256];
        __builtin_amdgcn_sched_barrier(0);
        #pragma unroll
        for (int q = 0; q < 4; ++q) {
            const float4 x4 = *reinterpret_cast<const float4*>(s_xh + r0 + 4 * q);
            const float xv[4] = {x4.x, x4.y, x4.z, x4.w};
            #pragma unroll
            for (int j = 0; j < 4; ++j) {
                const float4 wv = w[4 * q + j];
                zi = fmaf(xv[j], wv.x, zi);
                zj = fmaf(xv[j], wv.y, zj);
                zf = fmaf(xv[j], wv.z, zf);
                zo = fmaf(xv[j], wv.w, zo);
            }
        }
    }
    const float nc = c * sigm(zf) + sigm(zi) * tanhf(zj);
    c = nc;
    return tanhf(nc) * sigm(zo);
}

template<bool F32>
__device__ __forceinline__ float4 load_bias4(const void* b, int u) {
    // gates i|j|f|o at cols u, 256+u, 512+u, 768+u; forget bias folded in.
    return make_float4(ld1<F32>(b, u), ld1<F32>(b, 256 + u),
                       ld1<F32>(b, 512 + u) + 1.0f, ld1<F32>(b, 768 + u));
}

__device__ __forceinline__ float4 zx_load(const uint2* __restrict__ zx, size_t n, int u) {
    const uint2 v = zx[n * 256 + u];
    const float2 ij = unp2h(v.x);
    const float2 fo = unp2h(v.y);
    return make_float4(ij.x, ij.y, fo.x, fo.y);
}

// ---------------------------------------------------------------------------
// Fallback tree (256-thread, pkf rows [0,512), gates i|j|o|f)
// ---------------------------------------------------------------------------
template<bool F32>
__device__ void run_tree_f4(int b, const P& p, float* smem) {
    const int u = threadIdx.x;
    float* s_x  = smem;          // 256
    float* s_hj = smem + 256;    // 256
    float* s_hk = smem + 512;    // 1024
    float* H = p.H;
    float* C = p.C;
    H[(size_t)b * UU + u] = 0.f;
    C[(size_t)b * UU + u] = 0.f;

    const float4* __restrict__ Wt = p.pkf + u;                 // x rows [0,256)
    const float4* __restrict__ Wh = Wt + (size_t)256 * 256;    // h rows [256,512)
    const float bi = ld1<F32>(p.tree_b, u);
    const float bj = ld1<F32>(p.tree_b, 256 + u);
    const float bo = ld1<F32>(p.tree_b, 512 + u);
    const float bf = ld1<F32>(p.tree_b, 768 + u) + 1.0f;

    for (int i = 0; i < TT; ++i) {
        const int* co = p.children_order + ((size_t)b * TT + i) * KK;
        const int i0 = co[0], i1 = co[1], i2 = co[2], i3 = co[3];
        const float h0 = H[((size_t)i0 * BB + b) * UU + u];
        const float h1 = H[((size_t)i1 * BB + b) * UU + u];
        const float h2 = H[((size_t)i2 * BB + b) * UU + u];
        const float h3 = H[((size_t)i3 * BB + b) * UU + u];
        const float c0 = C[((size_t)i0 * BB + b) * UU + u];
        const float c1 = C[((size_t)i1 * BB + b) * UU + u];
        const float c2 = C[((size_t)i2 * BB + b) * UU + u];
        const float c3 = C[((size_t)i3 * BB + b) * UU + u];
        s_x[u]        = p.tree_e[((size_t)b * TT + i) * UU + u];
        s_hk[u]       = h0;
        s_hk[256 + u] = h1;
        s_hk[512 + u] = h2;
        s_hk[768 + u] = h3;
        s_hj[u]       = h0 + h1 + h2 + h3;
        __syncthreads();

        float zi = bi, zj = bj, zo = bo, fx = bf;
        for (int r0 = 0; r0 < 256; r0 += 16) {        // x rows
            float4 w[16];
            #pragma unroll
            for (int k = 0; k < 16; ++k) w[k] = Wt[(size_t)(r0 + k) * 256];
            __builtin_amdgcn_sched_barrier(0);
            #pragma unroll
            for (int q = 0; q < 4; ++q) {
                const float4 x4 = *reinterpret_cast<const float4*>(s_x + r0 + 4 * q);
                const float xv[4] = {x4.x, x4.y, x4.z, x4.w};
                #pragma unroll
                for (int j = 0; j < 4; ++j) {
                    const float4 wv = w[4 * q + j];
                    zi = fmaf(xv[j], wv.x, zi);
                    zj = fmaf(xv[j], wv.y, zj);
                    zo = fmaf(xv[j], wv.z, zo);
                    fx = fmaf(xv[j], wv.w, fx);
                }
            }
        }
        float f0 = 0.f, f1 = 0.f, f2 = 0.f, f3 = 0.f;
        for (int r0 = 0; r0 < 256; r0 += 16) {        // h rows
            float4 w[16];
            #pragma unroll
            for (int k = 0; k < 16; ++k) w[k] = Wh[(size_t)(r0 + k) * 256];
            __builtin_amdgcn_sched_barrier(0);
            #pragma unroll
            for (int q = 0; q < 4; ++q) {
                const int r = r0 + 4 * q;
                const float4 hj4 = *reinterpret_cast<const float4*>(s_hj + r);
                const float4 a0  = *reinterpret_cast<const float4*>(s_hk + r);
                const float4 a1  = *reinterpret_cast<const float4*>(s_hk + 256 + r);
                const float4 a2  = *reinterpret_cast<const float4*>(s_hk + 512 + r);
                const float4 a3  = *reinterpret_cast<const float4*>(s_hk + 768 + r);
                const float hjv[4] = {hj4.x, hj4.y, hj4.z, hj4.w};
                const float k0[4]  = {a0.x, a0.y, a0.z, a0.w};
                const float k1[4]  = {a1.x, a1.y, a1.z, a1.w};
                const float k2[4]  = {a2.x, a2.y, a2.z, a2.w};
                const float k3[4]  = {a3.x, a3.y, a3.z, a3.w};
                #pragma unroll
                for (int j = 0; j < 4; ++j) {
                    const float4 wv = w[4 * q + j];
                    zi = fmaf(hjv[j], wv.x, zi);
                    zj = fmaf(hjv[j], wv.y, zj);
                    zo = fmaf(hjv[j], wv.z, zo);
                    f0 = fmaf(k0[j], wv.w, f0);
                    f1 = fmaf(k1[j], wv.w, f1);
                    f2 = fmaf(k2[j], wv.w, f2);
                    f3 = fmaf(k3[j], wv.w, f3);
                }
            }
        }
        const float fsum = c0 * sigm(fx + f0) + c1 * sigm(fx + f1)
                         + c2 * sigm(fx + f2) + c3 * sigm(fx + f3);
        const float nc = fsum + sigm(zi) * tanhf(zj);
        const float nh = tanhf(nc) * sigm(zo);
        __syncthreads();
        H[((size_t)(i + 1) * BB + b) * UU + u] = nh;
        C[((size_t)(i + 1) * BB + b) * UU + u] = nc;
    }
}

// ===========================================================================
// FALLBACK (round-2) fused chains — used when workspace is too small
// ===========================================================================
template<bool F32>
__device__ void run_token_l0_f4(int b, const P& p, float* smem, bool is_bw) {
    const int u = threadIdx.x;
    float* s_xh = smem;
    const int len = p.token_length[b];
    const float4* __restrict__ Wp = p.pkf + (size_t)(is_bw ? OFF_BW0 : OFF_FW0) * 256 + u;
    const float4 bz = load_bias4<F32>(is_bw ? p.bw0_b : p.fw0_b, u);

    float c0 = 0.f;
    s_xh[256 + u] = 0.f;
    for (int t = 0; t < len; ++t) {
        const int row = is_bw ? (len - 1 - t) : t;
        s_xh[u] = bf2f(p.token_e[((size_t)b * LL + row) * UU + u]);
        __syncthreads();
        const float nh = lstm_step_f4<512>(Wp, bz, s_xh, c0);
        p.x1[((size_t)b * LL + row) * 512 + (is_bw ? 256 : 0) + u] = f2bf(nh);
        __syncthreads();
        s_xh[256 + u] = nh;
    }
}

template<bool F32>
__device__ void run_act_dq_f4(int b, const P& p, float* smem) {
    const int u = threadIdx.x;
    float* s_xh0 = smem;
    float* s_xh1 = smem + 512;

    {
        const int len = p.history_action_length[b];
        const float4* __restrict__ W0 = p.pkf + (size_t)OFF_ACT0 * 256 + u;
        const float4* __restrict__ W1 = p.pkf + (size_t)OFF_ACT1 * 256 + u;
        const float4 bz0 = load_bias4<F32>(p.act0_b, u);
        const float4 bz1 = load_bias4<F32>(p.act1_b, u);
        float ca0 = 0.f, ca1 = 0.f, h1last = 0.f;
        s_xh0[ADIM + u] = 0.f;
        s_xh1[256 + u]  = 0.f;
        for (int t = 0; t < len; ++t) {
            const int aid = p.history_action_id[b * AA + t];
            if (u < ADIM) s_xh0[u] = ld1<F32>(p.act_emb, (size_t)aid * ADIM + u);
            __syncthreads();
            const float nh0 = lstm_step_f4<320>(W0, bz0, s_xh0, ca0);
            __syncthreads();
            s_xh0[ADIM + u] = nh0;
            s_xh1[u]        = nh0;
            __syncthreads();
            const float nh1 = lstm_step_f4<512>(W1, bz1, s_xh1, ca1);
            __syncthreads();
            s_xh1[256 + u] = nh1;
            h1last = nh1;
        }
        p.act_h[b * UU + u] = h1last;
    }
    __syncthreads();
    {
        const int len = p.deque_length[b];
        const float4* __restrict__ W0 = p.pkf + (size_t)OFF_DQ0 * 256 + u;
        const float4* __restrict__ W1 = p.pkf + (size_t)OFF_DQ1 * 256 + u;
        const float4 bz0 = load_bias4<F32>(p.dq0_b, u);
        const float4 bz1 = load_bias4<F32>(p.dq1_b, u);
        float cd0 = 0.f, cd1 = 0.f, h1last = 0.f;
        s_xh0[256 + u] = 0.f;
        s_xh1[256 + u] = 0.f;
        for (int t = 0; t < len; ++t) {
            s_xh0[u] = bf2f(p.deque_e[((size_t)b * DQN + t) * UU + u]);
            __syncthreads();
            const float nh0 = lstm_step_f4<512>(W0, bz0, s_xh0, cd0);
            __syncthreads();
            s_xh0[256 + u] = nh0;
            s_xh1[u]       = nh0;
            __syncthreads();
            const float nh1 = lstm_step_f4<512>(W1, bz1, s_xh1, cd1);
            __syncthreads();
            s_xh1[256 + u] = nh1;
            h1last = nh1;
        }
        p.dq_h[b * UU + u] = h1last;
    }
}

__global__ __launch_bounds__(256) void phase1_fb_kernel(P p) {
    __shared__ __align__(16) float smem[1536];
    const bool f32 = (p.flag[0] == 1);
    const int chain = blockIdx.x & 3;
    const int b     = blockIdx.x >> 2;
    if (f32) {
        if (chain == 0)      run_tree_f4<true>(b, p, smem);
        else if (chain == 1) run_token_l0_f4<true>(b, p, smem, false);
        else if (chain == 2) run_token_l0_f4<true>(b, p, smem, true);
        else                 run_act_dq_f4<true>(b, p, smem);
    } else {
        if (chain == 0)      run_tree_f4<false>(b, p, smem);
        else if (chain == 1) run_token_l0_f4<false>(b, p, smem, false);
        else if (chain == 2) run_token_l0_f4<false>(b, p, smem, true);
        else                 run_act_dq_f4<false>(b, p, smem);
    }
}

template<bool F32>
__device__ void run_stack_f4(int b, const P& p, float* smem) {
    const int u = threadIdx.x;
    float* s_xh0 = smem;
    float* s_xh1 = smem + 512;
    const int len = p.stack_length[b];
    const float4* __restrict__ W0 = p.pkf + (size_t)OFF_S0 * 256 + u;
    const float4* __restrict__ W1 = p.pkf + (size_t)OFF_S1 * 256 + u;
    const float4 bz0 = load_bias4<F32>(p.stack0_b, u);
    const float4 bz1 = load_bias4<F32>(p.stack1_b, u);
    float cs0 = 0.f, cs1 = 0.f, h1last = 0.f;
    s_xh0[256 + u] = 0.f;
    s_xh1[256 + u] = 0.f;
    for (int t = 0; t < len; ++t) {
        const int so = p.stack_order[b * SS + t];
        s_xh0[u] = p.H[((size_t)so * BB + b) * UU + u];
        __syncthreads();
        const float nh0 = lstm_step_f4<512>(W0, bz0, s_xh0, cs0);
        __syncthreads();
        s_xh0[256 + u] = nh0;
        s_xh1[u]       = nh0;
        __syncthreads();
        const float nh1 = lstm_step_f4<512>(W1, bz1, s_xh1, cs1);
        __syncthreads();
        s_xh1[256 + u] = nh1;
        h1last = nh1;
    }
    p.stack_h[b * UU + u] = h1last;
}

template<bool F32>
__device__ void run_token_l1_f4(int b, const P& p, float* smem, bool is_bw) {
    const int u = threadIdx.x;
    float* s_xh = smem;
    const int len  = p.token_length[b];
    const int btop = p.buff_top_id[b];
    const float4* __restrict__ Wp = p.pkf + (size_t)(is_bw ? OFF_BW1 : OFF_FW1) * 256 + u;
    const float4 bz = load_bias4<F32>(is_bw ? p.bw1_b : p.fw1_b, u);

    float c1 = 0.f, hlast = 0.f;
    s_xh[512 + u] = 0.f;
    for (int t = 0; t < len; ++t) {
        const int row = is_bw ? (len - 1 - t) : t;
        const ushort_t* xr = p.x1 + ((size_t)b * LL + row) * 512;
        s_xh[u]       = bf2f(xr[u]);
        s_xh[256 + u] = bf2f(xr[256 + u]);
        __syncthreads();
        const float nh = lstm_step_f4<768>(Wp, bz, s_xh, c1);
        if (!is_bw) {
            if (t == btop) p.fw_top[b * UU + u] = nh;
        } else {
            if (t == 0)              p.bw_bottom[b * UU + u] = nh;
            if (t == len - 1 - btop) p.bw_top[b * UU + u]    = nh;
        }
        __syncthreads();
        s_xh[512 + u] = nh;
        hlast = nh;
    }
    if (!is_bw) p.fw1_h[b * UU + u] = hlast;
}

__global__ __launch_bounds__(256) void phase2_fb_kernel(P p) {
    __shared__ __align__(16) float smem[1024];
    const bool f32 = (p.flag[0] == 1);
    const int chain = blockIdx.x % 3;
    const int b     = blockIdx.x / 3;
    if (f32) {
        if (chain == 0)      run_stack_f4<true>(b, p, smem);
        else if (chain == 1) run_token_l1_f4<true>(b, p, smem, false);
        else                 run_token_l1_f4<true>(b, p, smem, true);
    } else {
        if (chain == 0)      run_stack_f4<false>(b, p, smem);
        else if (chain == 1) run_token_l1_f4<false>(b, p, smem, false);
        else                 run_token_l1_f4<false>(b, p, smem, true);
    }
}

// ===========================================================================
// PLAN B — x-part precompute (xpre, 32-row tiles / 32 KB LDS)
// ===========================================================================
template<bool F32, int R>
__device__ void xpre_compute(const void* __restrict__ W, const void* __restrict__ bias,
                             uint2* __restrict__ zx, int n0,
                             const float* __restrict__ s_xf, const ushort_t* __restrict__ s_xb) {
    const int u = threadIdx.x;
    const float4 bz = load_bias4<F32>(bias, u);
    for (int c = 0; c < 32; c += 8) {
        float4 acc[8];
        #pragma unroll
        for (int n = 0; n < 8; ++n) acc[n] = bz;
        for (int r0 = 0; r0 < R; r0 += 8) {
            float4 w[8];
            #pragma unroll
            for (int k = 0; k < 8; ++k) {
                const size_t ro = (size_t)(r0 + k) * 1024;
                w[k] = make_float4(ld1<F32>(W, ro + u),
                                   ld1<F32>(W, ro + 256 + u),
                                   ld1<F32>(W, ro + 512 + u),
                                   ld1<F32>(W, ro + 768 + u));
            }
            #pragma unroll
            for (int n = 0; n < 8; ++n) {
                float xv[8];
                #pragma unroll
                for (int k = 0; k < 8; ++k)
                    xv[k] = (R == 512) ? bf2f(s_xb[(size_t)(c + n) * 512 + r0 + k])
                                       : s_xf[(size_t)(c + n) * R + r0 + k];
                #pragma unroll
                for (int k = 0; k < 8; ++k) {
                    acc[n].x = fmaf(xv[k], w[k].x, acc[n].x);
                    acc[n].y = fmaf(xv[k], w[k].y, acc[n].y);
                    acc[n].z = fmaf(xv[k], w[k].z, acc[n].z);
                    acc[n].w = fmaf(xv[k], w[k].w, acc[n].w);
                }
            }
        }
        #pragma unroll
        for (int n = 0; n < 8; ++n) {
            uint2 v;
            v.x = pack2h(acc[n].x, acc[n].y);
            v.y = pack2h(acc[n].z, acc[n].w);
            zx[(size_t)(n0 + c + n) * 256 + u] = v;
        }
    }
}

template<bool F32, int STAGE>
__device__ void xpre_impl(const P& p, char* s_raw) {
    float*    s_xf = reinterpret_cast<float*>(s_raw);
    ushort_t* s_xb = reinterpret_cast<ushort_t*>(s_raw);
    const int blk = blockIdx.x;
    const int tid = threadIdx.x;

    const void* W; const void* bias; uint2* zx; int R; int kind; int n0;
    if (STAGE == 0) {
        if (blk < 256)      { W=p.fw0_W;  bias=p.fw0_b;  zx=p.zxA; R=256; kind=0; n0=blk*32; }
        else if (blk < 512) { W=p.bw0_W;  bias=p.bw0_b;  zx=p.zxB; R=256; kind=0; n0=(blk-256)*32; }
        else if (blk < 640) { W=p.act0_W; bias=p.act0_b; zx=p.zxC; R=64;  kind=3; n0=(blk-512)*32; }
        else                { W=p.dq0_W;  bias=p.dq0_b;  zx=p.zxD; R=256; kind=1; n0=(blk-640)*32; }
    } else if (STAGE == 1) {
        if (blk < 256)      { W=p.fw1_W;    bias=p.fw1_b;    zx=p.zxA; R=512; kind=2; n0=blk*32; }
        else if (blk < 512) { W=p.bw1_W;    bias=p.bw1_b;    zx=p.zxB; R=512; kind=2; n0=(blk-256)*32; }
        else if (blk < 640) { W=p.stack0_W; bias=p.stack0_b; zx=p.zxS; R=256; kind=4; n0=(blk-512)*32; }
        else if (blk < 768) { W=p.act1_W;   bias=p.act1_b;   zx=p.zxC; R=256; kind=5; n0=(blk-640)*32; }
        else                { W=p.dq1_W;    bias=p.dq1_b;    zx=p.zxD; R=256; kind=6; n0=(blk-768)*32; }
    } else {
        W=p.stack1_W; bias=p.stack1_b; zx=p.zxS; R=256; kind=7; n0=blk*32;
    }

    // stage the 32-row x tile into LDS (max 32 KB)
    if (kind == 0 || kind == 1) {                 // bf16 linear, R=256
        const ushort_t* src = (kind == 0 ? p.token_e : p.deque_e) + (size_t)n0 * 256;
        for (int i = tid; i < 32 * 256; i += 256) s_xf[i] = bf2f(src[i]);
    } else if (kind == 2) {                       // x1 bf16, R=512 (kept bf16 in LDS)
        const ushort_t* src = p.x1 + (size_t)n0 * 512;
        for (int i = tid; i < 32 * 512; i += 256) s_xb[i] = src[i];
    } else if (kind == 3) {                       // act_emb gather, R=64 (rows/batch = AA)
        const int b = n0 >> 6, t0 = n0 & 63;
        for (int i = tid; i < 32 * 64; i += 256) {
            const int t = t0 + (i >> 6), r = i & 63;
            int aid = p.history_action_id[b * AA + t];
            aid = aid < 0 ? 0 : (aid > NAOUT - 1 ? NAOUT - 1 : aid);   // clamp: abort-proof
            s_xf[i] = ld1<F32>(p.act_emb, (size_t)aid * ADIM + r);
        }
    } else if (kind == 4) {                       // H gather (stack0), R=256 (rows/batch = SS)
        const int b = n0 >> 6, t0 = n0 & 63;
        for (int i = tid; i < 32 * 256; i += 256) {
            const int t = t0 + (i >> 8), r = i & 255;
            int so = p.stack_order[b * SS + t];
            so = so < 0 ? 0 : (so > TT ? TT : so);                     // clamp: abort-proof
            s_xf[i] = p.H[((size_t)so * BB + b) * UU + r];
        }
    } else {                                      // f32 linear h0-seqs, R=256
        const float* src = (kind == 5 ? p.a0_seq : kind == 6 ? p.d0_seq : p.s0_seq)
                         + (size_t)n0 * 256;
        for (int i = tid; i < 32 * 256; i += 256) s_xf[i] = src[i];
    }
    __syncthreads();

    if (R == 512)      xpre_compute<F32, 512>(W, bias, zx, n0, s_xf, s_xb);
    else if (R == 256) xpre_compute<F32, 256>(W, bias, zx, n0, s_xf, s_xb);
    else               xpre_compute<F32, 64 >(W, bias, zx, n0, s_xf, s_xb);
}

__global__ __launch_bounds__(256) void xpre0_kernel(P p) {
    __shared__ __align__(16) char s_raw[32768];
    if (p.flag[0] == 1) xpre_impl<true, 0>(p, s_raw);
    else                xpre_impl<false, 0>(p, s_raw);
}
__global__ __launch_bounds__(256) void xpre1_kernel(P p) {
    __shared__ __align__(16) char s_raw[32768];
    if (p.flag[0] == 1) xpre_impl<true, 1>(p, s_raw);
    else                xpre_impl<false, 1>(p, s_raw);
}
__global__ __launch_bounds__(256) void xpre2_kernel(P p) {
    __shared__ __align__(16) char s_raw[32768];
    if (p.flag[0] == 1) xpre_impl<true, 2>(p, s_raw);
    else                xpre_impl<false, 2>(p, s_raw);
}

// ===========================================================================
// PLAN B recurrences — 1024-thread row-split blocks.
// thread t: u = t&255 (output unit), rq = t>>8 (row quarter).
// Each rq computes a partial z over its row chunk into LDS; rq0 reduces,
// applies gates, owns ALL global H/C traffic (same-thread RAW coherence).
// ===========================================================================

// partial over 64 rows for h-only chains: returns float4 {zi,zj,zf,zo} partial
__device__ __forceinline__ float4 part64(const float4* __restrict__ W_u, int base,
                                         const float* __restrict__ s_h) {
    float4 acc = make_float4(0.f, 0.f, 0.f, 0.f);
    for (int r0 = 0; r0 < 64; r0 += 8) {
        float4 w[8];
        #pragma unroll
        for (int k = 0; k < 8; ++k) w[k] = W_u[(size_t)(base + r0 + k) * 256];
        __builtin_amdgcn_sched_barrier(0);
        #pragma unroll
        for (int q = 0; q < 2; ++q) {
            const float4 x4 = *reinterpret_cast<const float4*>(s_h + base + r0 + 4 * q);
            const float xv[4] = {x4.x, x4.y, x4.z, x4.w};
            #pragma unroll
            for (int j = 0; j < 4; ++j) {
                const float4 wv = w[4 * q + j];
                acc.x = fmaf(xv[j], wv.x, acc.x);
                acc.y = fmaf(xv[j], wv.y, acc.y);
                acc.z = fmaf(xv[j], wv.z, acc.z);
                acc.w = fmaf(xv[j], wv.w, acc.w);
            }
        }
    }
    return acc;
}

// One h-only LSTM step, row-split. Returns nh (valid on rq0 only).
// Caller must: if (rq==0) { s_h[u] = nh; ...outputs... }  __syncthreads();
__device__ __forceinline__ float hstep(const float4* __restrict__ W_u,
                                       const uint2* __restrict__ zx, size_t n,
                                       float* s_h, float* s_pt,
                                       float& c, int u, int rq) {
    float4 bz = make_float4(0.f, 0.f, 0.f, 0.f);
    if (rq == 0) bz = zx_load(zx, n, u);          // issue early; used after barrier
    const float4 acc = part64(W_u, rq << 6, s_h);
    *reinterpret_cast<float4*>(s_pt + (((rq << 8) + u) << 2)) = acc;
    __syncthreads();
    float nh = 0.f;
    if (rq == 0) {
        const float4 P0 = *reinterpret_cast<const float4*>(s_pt + ((u)        << 2));
        const float4 P1 = *reinterpret_cast<const float4*>(s_pt + ((256 + u)  << 2));
        const float4 P2 = *reinterpret_cast<const float4*>(s_pt + ((512 + u)  << 2));
        const float4 P3 = *reinterpret_cast<const float4*>(s_pt + ((768 + u)  << 2));
        const float zi = bz.x + P0.x + P1.x + P2.x + P3.x;
        const float zj = bz.y + P0.y + P1.y + P2.y + P3.y;
        const float zf = bz.z + P0.z + P1.z + P2.z + P3.z;
        const float zo = bz.w + P0.w + P1.w + P2.w + P3.w;
        const float nc = c * sigm(zf) + sigm(zi) * tanhf(zj);
        c = nc;
        nh = tanhf(nc) * sigm(zo);
    }
    return nh;
}

// ---------------------------------------------------------------------------
// Tree, 1024-thread. x rows split over rq0-1 (128 each), h rows over rq2-3.
// rq0 owns all global H/C loads & stores (coherent by program order).
// ---------------------------------------------------------------------------
template<bool F32>
__device__ void run_tree_1024(int b, const P& p, float* smem) {
    const int t = threadIdx.x;
    const int u = t & 255, rq = t >> 8;
    float* s_x  = smem;            // 256
    float* s_hk = smem + 256;      // 1024
    float* s_pt = smem + 1280;     // 4*256*8 = 8192
    float* H = p.H;
    float* C = p.C;
    if (rq == 0) {
        H[(size_t)b * UU + u] = 0.f;
        C[(size_t)b * UU + u] = 0.f;
    }
    const float4* __restrict__ Wt = p.pkf + u;
    const float4* __restrict__ Wh = Wt + (size_t)256 * 256;
    const float bi = ld1<F32>(p.tree_b, u);
    const float bj = ld1<F32>(p.tree_b, 256 + u);
    const float bo = ld1<F32>(p.tree_b, 512 + u);
    const float bf = ld1<F32>(p.tree_b, 768 + u) + 1.0f;
    __syncthreads();

    for (int i = 0; i < TT; ++i) {
        const int* co = p.children_order + ((size_t)b * TT + i) * KK;
        float c0 = 0.f, c1 = 0.f, c2 = 0.f, c3 = 0.f;
        if (rq == 0) {
            const int i0 = co[0], i1 = co[1], i2 = co[2], i3 = co[3];
            const float h0 = H[((size_t)i0 * BB + b) * UU + u];
            const float h1 = H[((size_t)i1 * BB + b) * UU + u];
            const float h2 = H[((size_t)i2 * BB + b) * UU + u];
            const float h3 = H[((size_t)i3 * BB + b) * UU + u];
            c0 = C[((size_t)i0 * BB + b) * UU + u];
            c1 = C[((size_t)i1 * BB + b) * UU + u];
            c2 = C[((size_t)i2 * BB + b) * UU + u];
            c3 = C[((size_t)i3 * BB + b) * UU + u];
            s_hk[u]       = h0;
            s_hk[256 + u] = h1;
            s_hk[512 + u] = h2;
            s_hk[768 + u] = h3;
        } else if (rq == 1) {
            s_x[u] = p.tree_e[((size_t)b * TT + i) * UU + u];
        }
        __syncthreads();

        float p0, p1, p2, p3, p4, p5, p6, p7;
        if (rq < 2) {                             // x rows [rq*128, +128)
            float zi = 0.f, zj = 0.f, zo = 0.f, fx = 0.f;
            const int base = rq << 7;
            for (int r0 = 0; r0 < 128; r0 += 8) {
                float4 w[8];
                #pragma unroll
                for (int k = 0; k < 8; ++k) w[k] = Wt[(size_t)(base + r0 + k) * 256];
                __builtin_amdgcn_sched_barrier(0);
                #pragma unroll
                for (int q = 0; q < 2; ++q) {
                    const float4 x4 = *reinterpret_cast<const float4*>(s_x + base + r0 + 4 * q);
                    const float xv[4] = {x4.x, x4.y, x4.z, x4.w};
                    #pragma unroll
                    for (int j = 0; j < 4; ++j) {
                        const float4 wv = w[4 * q + j];
                        zi = fmaf(xv[j], wv.x, zi);
                        zj = fmaf(xv[j], wv.y, zj);
                        zo = fmaf(xv[j], wv.z, zo);
                        fx = fmaf(xv[j], wv.w, fx);
                    }
                }
            }
            p0 = zi; p1 = zj; p2 = zo; p3 = fx;
            p4 = 0.f; p5 = 0.f; p6 = 0.f; p7 = 0.f;
        } else {                                  // h rows [(rq-2)*128, +128)
            float zi = 0.f, zj = 0.f, zo = 0.f;
            float f0 = 0.f, f1 = 0.f, f2 = 0.f, f3 = 0.f;
            const int base = (rq - 2) << 7;
            for (int r0 = 0; r0 < 128; r0 += 8) {
                float4 w[8];
                #pragma unroll
                for (int k = 0; k < 8; ++k) w[k] = Wh[(size_t)(base + r0 + k) * 256];
                __builtin_amdgcn_sched_barrier(0);
                #pragma unroll
                for (int q = 0; q < 2; ++q) {
                    const int r = base + r0 + 4 * q;
                    const float4 a0 = *reinterpret_cast<const float4*>(s_hk + r);
                    const float4 a1 = *reinterpret_cast<const float4*>(s_hk + 256 + r);
                    const float4 a2 = *reinterpret_cast<const float4*>(s_hk + 512 + r);
                    const float4 a3 = *reinterpret_cast<const float4*>(s_hk + 768 + r);
                    const float hj[4] = {a0.x + a1.x + a2.x + a3.x,
                                         a0.y + a1.y + a2.y + a3.y,
                                         a0.z + a1.z + a2.z + a3.z,
                                         a0.w + a1.w + a2.w + a3.w};
                    const float k0[4] = {a0.x, a0.y, a0.z, a0.w};
                    const float k1[4] = {a1.x, a1.y, a1.z, a1.w};
                    const float k2[4] = {a2.x, a2.y, a2.z, a2.w};
                    const float k3[4] = {a3.x, a3.y, a3.z, a3.w};
                    #pragma unroll
                    for (int j = 0; j < 4; ++j) {
                        const float4 wv = w[4 * q + j];
                        zi = fmaf(hj[j], wv.x, zi);
                        zj = fmaf(hj[j], wv.y, zj);
                        zo = fmaf(hj[j], wv.z, zo);
                        f0 = fmaf(k0[j], wv.w, f0);
                        f1 = fmaf(k1[j], wv.w, f1);
                        f2 = fmaf(k2[j], wv.w, f2);
                        f3 = fmaf(k3[j], wv.w, f3);
                    }
                }
            }
            p0 = zi; p1 = zj; p2 = zo; p3 = 0.f;
            p4 = f0; p5 = f1; p6 = f2; p7 = f3;
        }
        float* pt = s_pt + (((rq << 8) + u) << 3);
        *reinterpret_cast<float4*>(pt)     = make_float4(p0, p1, p2, p3);
        *reinterpret_cast<float4*>(pt + 4) = make_float4(p4, p5, p6, p7);
        __syncthreads();
        if (rq == 0) {
            float4 A[4], Bv[4];
            #pragma unroll
            for (int g = 0; g < 4; ++g) {
                const float* q_ = s_pt + (((g << 8) + u) << 3);
                A[g]  = *reinterpret_cast<const float4*>(q_);
                Bv[g] = *reinterpret_cast<const float4*>(q_ + 4);
            }
            const float zi = bi + A[0].x + A[1].x + A[2].x + A[3].x;
            const float zj = bj + A[0].y + A[1].y + A[2].y + A[3].y;
            const float zo = bo + A[0].z + A[1].z + A[2].z + A[3].z;
            const float fx = bf + A[0].w + A[1].w + A[2].w + A[3].w;
            const float f0 = Bv[0].x + Bv[1].x + Bv[2].x + Bv[3].x;
            const float f1 = Bv[0].y + Bv[1].y + Bv[2].y + Bv[3].y;
            const float f2 = Bv[0].z + Bv[1].z + Bv[2].z + Bv[3].z;
            const float f3 = Bv[0].w + Bv[1].w + Bv[2].w + Bv[3].w;
            const float fsum = c0 * sigm(fx + f0) + c1 * sigm(fx + f1)
                             + c2 * sigm(fx + f2) + c3 * sigm(fx + f3);
            const float nc = fsum + sigm(zi) * tanhf(zj);
            const float nh = tanhf(nc) * sigm(zo);
            H[((size_t)(i + 1) * BB + b) * UU + u] = nh;
            C[((size_t)(i + 1) * BB + b) * UU + u] = nc;
        }
        __syncthreads();
    }
}

// ---------------------------------------------------------------------------
// Plan-B phase 1 (1024T): {tree, fw0-h, bw0-h, act0-h, dq0-h}
// ---------------------------------------------------------------------------
template<bool F32>
__device__ void p1_impl(const P& p, float* smem) {
    const int chain = blockIdx.x >> 6;
    const int b     = blockIdx.x & 63;
    if (chain == 0) { run_tree_1024<F32>(b, p, smem); return; }

    const int t = threadIdx.x;
    const int u = t & 255, rq = t >> 8;
    float* s_h  = smem;
    float* s_pt = smem + 256;
    float c = 0.f;
    if (rq == 0) s_h[u] = 0.f;
    __syncthreads();

    if (chain == 1 || chain == 2) {               // token layer 0
        const bool bw = (chain == 2);
        const int len = p.token_length[b];
        const float4* __restrict__ Wh = p.pkf + (size_t)(bw ? PKH_BW0 : PKH_FW0) * 256 + u;
        const uint2* zx = bw ? p.zxB : p.zxA;
        for (int tt = 0; tt < len; ++tt) {
            const int row = bw ? (len - 1 - tt) : tt;
            const float nh = hstep(Wh, zx, (size_t)b * LL + row, s_h, s_pt, c, u, rq);
            if (rq == 0) {
                p.x1[((size_t)b * LL + row) * 512 + (bw ? 256 : 0) + u] = f2bf(nh);
                s_h[u] = nh;
            }
            __syncthreads();
        }
    } else if (chain == 3) {                      // act layer 0
        const int len = p.history_action_length[b];
        const float4* __restrict__ Wh = p.pkf + (size_t)PKH_ACT0 * 256 + u;
        for (int tt = 0; tt < len; ++tt) {
            const float nh = hstep(Wh, p.zxC, (size_t)b * AA + tt, s_h, s_pt, c, u, rq);
            if (rq == 0) {
                p.a0_seq[((size_t)b * AA + tt) * UU + u] = nh;
                s_h[u] = nh;
            }
            __syncthreads();
        }
    } else {                                      // deque layer 0
        const int len = p.deque_length[b];
        const float4* __restrict__ Wh = p.pkf + (size_t)PKH_DQ0 * 256 + u;
        for (int tt = 0; tt < len; ++tt) {
            const float nh = hstep(Wh, p.zxD, (size_t)b * DQN + tt, s_h, s_pt, c, u, rq);
            if (rq == 0) {
                p.d0_seq[((size_t)b * DQN + tt) * UU + u] = nh;
                s_h[u] = nh;
            }
            __syncthreads();
        }
    }
}

__global__ __launch_bounds__(1024) void p1_kernel(P p) {
    __shared__ __align__(16) float smem[9472];
    if (p.flag[0] == 1) p1_impl<true>(p, smem);
    else                p1_impl<false>(p, smem);
}

// ---------------------------------------------------------------------------
// Plan-B phase 2 (1024T): {fw1-h, bw1-h, stack0-h, act1-h, dq1-h}
// ---------------------------------------------------------------------------
template<bool F32>
__device__ void p2_impl(const P& p, float* smem) {
    const int chain = blockIdx.x >> 6;
    const int b     = blockIdx.x & 63;
    const int t = threadIdx.x;
    const int u = t & 255, rq = t >> 8;
    float* s_h  = smem;
    float* s_pt = smem + 256;
    float c = 0.f;
    if (rq == 0) s_h[u] = 0.f;
    __syncthreads();

    if (chain == 0) {                             // fw1
        const int len  = p.token_length[b];
        const int btop = p.buff_top_id[b];
        const float4* __restrict__ Wh = p.pkf + (size_t)PKH_FW1 * 256 + u;
        float hlast = 0.f;
        for (int tt = 0; tt < len; ++tt) {
            const float nh = hstep(Wh, p.zxA, (size_t)b * LL + tt, s_h, s_pt, c, u, rq);
            if (rq == 0) {
                if (tt == btop) p.fw_top[b * UU + u] = nh;
                s_h[u] = nh;
                hlast = nh;
            }
            __syncthreads();
        }
        if (rq == 0) p.fw1_h[b * UU + u] = hlast;
    } else if (chain == 1) {                      // bw1
        const int len  = p.token_length[b];
        const int btop = p.buff_top_id[b];
        const float4* __restrict__ Wh = p.pkf + (size_t)PKH_BW1 * 256 + u;
        for (int tt = 0; tt < len; ++tt) {
            const int row = len - 1 - tt;
            const float nh = hstep(Wh, p.zxB, (size_t)b * LL + row, s_h, s_pt, c, u, rq);
            if (rq == 0) {
                if (tt == 0)              p.bw_bottom[b * UU + u] = nh;
                if (tt == len - 1 - btop) p.bw_top[b * UU + u]    = nh;
                s_h[u] = nh;
            }
            __syncthreads();
        }
    } else if (chain == 2) {                      // stack layer 0
        const int len = p.stack_length[b];
        const float4* __restrict__ Wh = p.pkf + (size_t)PKH_S0 * 256 + u;
        for (int tt = 0; tt < len; ++tt) {
            const float nh = hstep(Wh, p.zxS, (size_t)b * SS + tt, s_h, s_pt, c, u, rq);
            if (rq == 0) {
                p.s0_seq[((size_t)b * SS + tt) * UU + u] = nh;
                s_h[u] = nh;
            }
            __syncthreads();
        }
    } else if (chain == 3) {                      // act layer 1
        const int len = p.history_action_length[b];
        const float4* __restrict__ Wh = p.pkf + (size_t)PKH_ACT1 * 256 + u;
        float hlast = 0.f;
        for (int tt = 0; tt < len; ++tt) {
            const float nh = hstep(Wh, p.zxC, (size_t)b * AA + tt, s_h, s_pt, c, u, rq);
            if (rq == 0) { s_h[u] = nh; hlast = nh; }
            __syncthreads();
        }
        if (rq == 0) p.act_h[b * UU + u] = hlast;
    } else {                                      // deque layer 1
        const int len = p.deque_length[b];
        const float4* __restrict__ Wh = p.pkf + (size_t)PKH_DQ1 * 256 + u;
        float hlast = 0.f;
        for (int tt = 0; tt < len; ++tt) {
            const float nh = hstep(Wh, p.zxD, (size_t)b * DQN + tt, s_h, s_pt, c, u, rq);
            if (rq == 0) { s_h[u] = nh; hlast = nh; }
            __syncthreads();
        }
        if (rq == 0) p.dq_h[b * UU + u] = hlast;
    }
}

__global__ __launch_bounds__(1024) void p2_kernel(P p) {
    __shared__ __align__(16) float smem[4352];
    if (p.flag[0] == 1) p2_impl<true>(p, smem);
    else                p2_impl<false>(p, smem);
}

// ---------------------------------------------------------------------------
// Plan-B phase 3 (1024T): stack layer 1
// ---------------------------------------------------------------------------
template<bool F32>
__device__ void p3_impl(const P& p, float* smem) {
    const int b = blockIdx.x;
    const int t = threadIdx.x;
    const int u = t & 255, rq = t >> 8;
    float* s_h  = smem;
    float* s_pt = smem + 256;
    float c = 0.f;
    if (rq == 0) s_h[u] = 0.f;
    __syncthreads();
    const int len = p.stack_length[b];
    const float4* __restrict__ Wh = p.pkf + (size_t)PKH_S1 * 256 + u;
    float hlast = 0.f;
    for (int tt = 0; tt < len; ++tt) {
        const float nh = hstep(Wh, p.zxS, (size_t)b * SS + tt, s_h, s_pt, c, u, rq);
        if (rq == 0) { s_h[u] = nh; hlast = nh; }
        __syncthreads();
    }
    if (rq == 0) p.stack_h[b * UU + u] = hlast;
}

__global__ __launch_bounds__(1024) void p3_kernel(P p) {
    __shared__ __align__(16) float smem[4352];
    if (p.flag[0] == 1) p3_impl<true>(p, smem);
    else                p3_impl<false>(p, smem);
}

// ---------------------------------------------------------------------------
// Final + pipeline tracers
// ---------------------------------------------------------------------------
template<bool F32>
__device__ __forceinline__ void st_out(void* out, int i, float v) {
    if constexpr (F32) reinterpret_cast<float*>(out)[i] = v;
    else               reinterpret_cast<__hip_bfloat16*>(out)[i] = __float2bfloat16(v);
}

template<bool F32>
__device__ void final_impl(const P& p, void* out, float* s_f) {
    const int b = blockIdx.x;
    const int u = threadIdx.x;
    s_f[u]        = p.stack_h[b * UU + u];
    s_f[256 + u]  = p.fw1_h[b * UU + u] - p.fw_top[b * UU + u];
    s_f[512 + u]  = p.bw_top[b * UU + u] - p.bw_bottom[b * UU + u];
    s_f[768 + u]  = p.act_h[b * UU + u];
    s_f[1024 + u] = p.dq_h[b * UU + u];
    __syncthreads();
    if (u < NAOUT) {
        float acc = ld1<F32>(p.fin_b, u);
        for (int r = 0; r < 1280; ++r)
            acc = fmaf(s_f[r], ld1<F32>(p.fin_W, (size_t)r * NAOUT + u), acc);
        acc = fmaxf(acc, 0.f);
        st_out<F32>(out, b * NAOUT + u, acc);
    }
    if (b == 0 && u == 0) {
        const uint_t POIS = 0xAAAAAAAAu;
        const uint_t* te = reinterpret_cast<const uint_t*>(p.tree_e);
        const uint_t* x1 = reinterpret_cast<const uint_t*>(p.x1);
        const uint_t* sh = reinterpret_cast<const uint_t*>(p.stack_h);
        bool te_p = true, x1_p = true;
        for (int i = 0; i < 8; ++i) { te_p &= (te[i] == POIS); x1_p &= (x1[i] == POIS); }
        bool sh_p = (sh[0] == POIS) && (sh[1] == POIS);
        float sent = 0.f;
        if (te_p)      sent = 3000.f;
        else if (x1_p) sent = 4000.f;
        else if (sh_p) sent = 5000.f;
        else if (*reinterpret_cast<const uint_t*>(p.flag) == POIS) sent = 6000.f;
        if (sent > 0.f) st_out<F32>(out, 0, sent);
    }
}

__global__ __launch_bounds__(256) void final_kernel(P p, void* out) {
    __shared__ __align__(16) float s_f[1280];
    if (p.flag[0] == 1) final_impl<true>(p, out, s_f);
    else                final_impl<false>(p, out, s_f);
}

// ---------------------------------------------------------------------------
extern "C" void kernel_launch(void* const* d_in, const int* in_sizes, int n_in,
                              void* d_out, int out_size, void* d_ws, size_t ws_size,
                              hipStream_t stream) {
    if (n_in != 43) {
        sentinel_kernel<<<1, 64, 0, stream>>>(d_out, 9000.f + (float)n_in);
        return;
    }
    if (out_size != NAOUT * BB) {
        sentinel_kernel<<<1, 64, 0, stream>>>(d_out, 8000.f);
        return;
    }

    P p;
    p.tree_word_id          = (const int*)d_in[0];
    p.tree_pos_id           = (const int*)d_in[1];
    p.token_word_id         = (const int*)d_in[2];
    p.token_pos_id          = (const int*)d_in[3];
    p.history_action_id     = (const int*)d_in[4];
    p.buff_top_id           = (const int*)d_in[5];
    p.deque_word_id         = (const int*)d_in[6];
    p.deque_pos_id          = (const int*)d_in[7];
    p.deque_length          = (const int*)d_in[8];
    p.children_order        = (const int*)d_in[9];
    p.stack_order           = (const int*)d_in[10];
    p.stack_length          = (const int*)d_in[11];
    p.token_length          = (const int*)d_in[12];
    p.history_action_length = (const int*)d_in[13];
    p.word_emb = d_in[14];
    p.pos_emb  = d_in[15];
    p.act_emb  = d_in[16];
    p.wd_W     = d_in[17];
    p.wd_b     = d_in[18];
    p.tree_W   = d_in[19];
    p.tree_b   = d_in[20];
    p.stack0_W = d_in[21];
    p.stack0_b = d_in[22];
    p.stack1_W = d_in[23];
    p.stack1_b = d_in[24];
    p.fw0_W    = d_in[25];
    p.fw0_b    = d_in[26];
    p.bw0_W    = d_in[27];
    p.bw0_b    = d_in[28];
    p.fw1_W    = d_in[29];
    p.fw1_b    = d_in[30];
    p.bw1_W    = d_in[31];
    p.bw1_b    = d_in[32];
    p.act0_W   = d_in[33];
    p.act0_b   = d_in[34];
    p.act1_W   = d_in[35];
    p.act1_b   = d_in[36];
    p.dq0_W    = d_in[37];
    p.dq0_b    = d_in[38];
    p.dq1_W    = d_in[39];
    p.dq1_b    = d_in[40];
    p.fin_W    = d_in[41];
    p.fin_b    = d_in[42];

    char* base = (char*)d_ws;

    // ---- Plan B layout (~112 MiB) ----
    size_t off = 0;
    p.flag = (int*)(base + off);           off += 256;
    p.stack_h   = (float*)(base + off);    off += (size_t)BB * UU * 4;
    p.fw1_h     = (float*)(base + off);    off += (size_t)BB * UU * 4;
    p.fw_top    = (float*)(base + off);    off += (size_t)BB * UU * 4;
    p.bw_top    = (float*)(base + off);    off += (size_t)BB * UU * 4;
    p.bw_bottom = (float*)(base + off);    off += (size_t)BB * UU * 4;
    p.act_h     = (float*)(base + off);    off += (size_t)BB * UU * 4;
    p.dq_h      = (float*)(base + off);    off += (size_t)BB * UU * 4;
    p.tree_e  = (float*)(base + off);      off += (size_t)BB * TT * UU * 4;
    p.token_e = (ushort_t*)(base + off);   off += (size_t)BB * LL * UU * 2;
    p.deque_e = (ushort_t*)(base + off);   off += (size_t)BB * DQN * UU * 2;
    p.x1      = (ushort_t*)(base + off);   off += (size_t)BB * LL * 512 * 2;
    p.a0_seq  = (float*)(base + off);      off += (size_t)BB * AA * UU * 4;
    p.d0_seq  = (float*)(base + off);      off += (size_t)BB * DQN * UU * 4;
    p.s0_seq  = (float*)(base + off);      off += (size_t)BB * SS * UU * 4;
    p.H       = (float*)(base + off);      off += (size_t)(TT + 1) * BB * UU * 4;
    p.C       = (float*)(base + off);      off += (size_t)(TT + 1) * BB * UU * 4;
    p.zxA     = (uint2*)(base + off);      off += (size_t)BB * LL * UU * 8;
    p.zxB     = (uint2*)(base + off);      off += (size_t)BB * LL * UU * 8;
    p.zxC     = (uint2*)(base + off);      off += (size_t)BB * AA * UU * 8;
    p.zxD     = (uint2*)(base + off);      off += (size_t)BB * DQN * UU * 8;
    p.zxS     = (uint2*)(base + off);      off += (size_t)BB * SS * UU * 8;
    p.pkf     = (float4*)(base + off);     off += (size_t)PK_ROWS_B * 256 * 16;
    const size_t planB_size = off;

    if (ws_size >= planB_size) {
        detect_kernel<<<1, 64, 0, stream>>>((const uint_t*)d_in[14], p.flag);
        pack_h_kernel<<<dim3(PK_ROWS_B), dim3(256), 0, stream>>>(p);
        embed_kernel<<<dim3(BB * TT + BB * LL + BB * DQN), dim3(256), 0, stream>>>(p);
        xpre0_kernel<<<dim3(704), dim3(256), 0, stream>>>(p);
        p1_kernel<<<dim3(5 * BB), dim3(1024), 0, stream>>>(p);
        xpre1_kernel<<<dim3(832), dim3(256), 0, stream>>>(p);
        p2_kernel<<<dim3(5 * BB), dim3(1024), 0, stream>>>(p);
        xpre2_kernel<<<dim3(128), dim3(256), 0, stream>>>(p);
        p3_kernel<<<dim3(BB), dim3(1024), 0, stream>>>(p);
        final_kernel<<<dim3(BB), dim3(256), 0, stream>>>(p, d_out);
        return;
    }

    // ---- Fallback: round-2 layout (~62 MiB) ----
    off = 0;
    p.flag = (int*)(base + off);           off += 16;
    p.stack_h   = (float*)(base + off);    off += (size_t)BB * UU * 4;
    p.fw1_h     = (float*)(base + off);    off += (size_t)BB * UU * 4;
    p.fw_top    = (float*)(base + off);    off += (size_t)BB * UU * 4;
    p.bw_top    = (float*)(base + off);    off += (size_t)BB * UU * 4;
    p.bw_bottom = (float*)(base + off);    off += (size_t)BB * UU * 4;
    p.act_h     = (float*)(base + off);    off += (size_t)BB * UU * 4;
    p.dq_h      = (float*)(base + off);    off += (size_t)BB * UU * 4;
    p.tree_e  = (float*)(base + off);      off += (size_t)BB * TT * UU * 4;
    p.token_e = (ushort_t*)(base + off);   off += (size_t)BB * LL * UU * 2;
    p.deque_e = (ushort_t*)(base + off);   off += (size_t)BB * DQN * UU * 2;
    p.x1      = (ushort_t*)(base + off);   off += (size_t)BB * LL * 512 * 2;
    p.H       = (float*)(base + off);      off += (size_t)(TT + 1) * BB * UU * 4;
    p.C       = (float*)(base + off);      off += (size_t)(TT + 1) * BB * UU * 4;
    p.pkf     = (float4*)(base + off);     off += (size_t)PK_ROWS_FB * 256 * 16;
    // unused in fallback, but keep valid pointers
    p.a0_seq = p.d0_seq = p.s0_seq = (float*)base;
    p.zxA = p.zxB = p.zxC = p.zxD = p.zxS = (uint2*)base;

    if (ws_size < off) {
        sentinel_kernel<<<1, 64, 0, stream>>>(d_out, 7000.f + (float)(ws_size >> 20));
        return;
    }

    detect_kernel<<<1, 64, 0, stream>>>((const uint_t*)d_in[14], p.flag);
    pack_fb_kernel<<<dim3(PK_ROWS_FB), dim3(256), 0, stream>>>(p);
    embed_kernel<<<dim3(BB * TT + BB * LL + BB * DQN), dim3(256), 0, stream>>>(p);
    phase1_fb_kernel<<<dim3(4 * BB), dim3(256), 0, stream>>>(p);
    phase2_fb_kernel<<<dim3(3 * BB), dim3(256), 0, stream>>>(p);
    final_kernel<<<dim3(BB), dim3(256), 0, stream>>>(p, d_out);
}

// Round 6
// 5103.349 us; speedup vs baseline: 2.0434x; 2.0434x over previous
//
#include <hip/hip_runtime.h>
#include <hip/hip_bf16.h>
#include <hip/hip_fp16.h>
#include <cstdint>

// Problem constants
#define BB   64
#define TT   128
#define KK   4
#define LL   128
#define SS   64
#define AA   64
#define DQN  32
#define UU   256
#define NAOUT 164
#define WDIM 300
#define PDIM 64
#define ADIM 64

// ---- Fallback (round-2) full-pack row offsets ----
#define OFF_TREE 0
#define OFF_S0   512
#define OFF_S1   1024
#define OFF_FW0  1536
#define OFF_BW0  2048
#define OFF_FW1  2560
#define OFF_BW1  3328
#define OFF_ACT0 4096
#define OFF_ACT1 4416
#define OFF_DQ0  4928
#define OFF_DQ1  5440
#define PK_ROWS_FB 5952

// ---- Plan-B/C pack: tree full (512 rows) + h-rows only for the rest ----
#define PKH_FW0  512
#define PKH_BW0  768
#define PKH_FW1  1024
#define PKH_BW1  1280
#define PKH_S0   1536
#define PKH_S1   1792
#define PKH_ACT0 2048
#define PKH_ACT1 2304
#define PKH_DQ0  2560
#define PKH_DQ1  2816
#define PK_ROWS_B 3072

typedef unsigned short ushort_t;
typedef unsigned int   uint_t;

__device__ __forceinline__ float bf2f(ushort_t s) {
    return __uint_as_float(((uint_t)s) << 16);
}
__device__ __forceinline__ ushort_t f2bf(float x) {
    __hip_bfloat16 h = __float2bfloat16(x);
    return *reinterpret_cast<ushort_t*>(&h);
}
__device__ __forceinline__ float sigm(float x) { return 1.0f / (1.0f + expf(-x)); }

__device__ __forceinline__ uint_t pack2h(float a, float b) {
    __half2 h = __floats2half2_rn(a, b);
    return *reinterpret_cast<uint_t*>(&h);
}
__device__ __forceinline__ float2 unp2h(uint_t v) {
    __half2 h = *reinterpret_cast<__half2*>(&v);
    return __half22float2(h);
}

// Dual-dtype load: F32=true -> buffer holds float32; false -> bf16.
template<bool F32>
__device__ __forceinline__ float ld1(const void* p_, size_t i) {
    if constexpr (F32) return reinterpret_cast<const float*>(p_)[i];
    else               return bf2f(reinterpret_cast<const ushort_t*>(p_)[i]);
}

struct P {
    // int inputs
    const int *tree_word_id, *tree_pos_id, *token_word_id, *token_pos_id, *history_action_id,
              *buff_top_id, *deque_word_id, *deque_pos_id, *deque_length, *children_order,
              *stack_order, *stack_length, *token_length, *history_action_length;
    // float-family params (dtype resolved at runtime)
    const void *word_emb, *pos_emb, *act_emb, *wd_W, *wd_b, *tree_W, *tree_b,
        *stack0_W, *stack0_b, *stack1_W, *stack1_b, *fw0_W, *fw0_b, *bw0_W, *bw0_b,
        *fw1_W, *fw1_b, *bw1_W, *bw1_b, *act0_W, *act0_b, *act1_W, *act1_b,
        *dq0_W, *dq0_b, *dq1_W, *dq1_b, *fin_W, *fin_b;
    // workspace
    int* flag;                          // [0]: 0 = bf16 world, 1 = f32 world
    float *stack_h, *fw1_h, *fw_top, *bw_top, *bw_bottom, *act_h, *dq_h;  // f32
    float *tree_e;                      // f32 (tree dynamics chaotic — f32 end-to-end)
    ushort_t *token_e, *deque_e, *x1;   // bf16
    float *H, *C;                       // f32
    float *a0_seq, *d0_seq, *s0_seq;    // f32 layer-0 h sequences
    // zx buffers: fp16x4 per (n, unit): x-part preactivations incl. bias (+forget bias)
    uint2 *zxA, *zxB, *zxC, *zxD, *zxS;
    float4* zxT;                        // tree x-part, f32x4 {i,j,o,f+b+1} (Plan C)
    // packed weights: float4 {g0,g1,g2,g3} per (row, u)
    float4* pkf;
};

// ---------------------------------------------------------------------------
__global__ void detect_kernel(const uint_t* w, int* flag) {
    __shared__ int cnt;
    if (threadIdx.x == 0) cnt = 0;
    __syncthreads();
    int local = 0;
    for (int i = threadIdx.x; i < 256; i += 64) {
        uint_t lo = w[i] & 0xFFFFu;
        uint_t e  = (lo >> 7) & 0xFFu;
        if (lo == 0u || (e >= 0x6Cu && e <= 0x7Fu)) local++;
    }
    atomicAdd(&cnt, local);
    __syncthreads();
    if (threadIdx.x == 0) flag[0] = (cnt >= 200) ? 0 : 1;
}

__global__ void sentinel_kernel(void* out, float v) {
    if (threadIdx.x == 0) {
        reinterpret_cast<float*>(out)[0] = v;
        reinterpret_cast<__hip_bfloat16*>(out)[2] = __float2bfloat16(v);
    }
}

// ---------------------------------------------------------------------------
// Weight packing — fallback (full rows)
// ---------------------------------------------------------------------------
__global__ __launch_bounds__(256) void pack_fb_kernel(P p) {
    const bool f32 = (p.flag[0] == 1);
    const int rg = blockIdx.x;
    const int u  = threadIdx.x;
    const void* src; int r;
    if      (rg < 512)  { src = p.tree_W;   r = rg; }
    else if (rg < 1024) { src = p.stack0_W; r = rg - 512; }
    else if (rg < 1536) { src = p.stack1_W; r = rg - 1024; }
    else if (rg < 2048) { src = p.fw0_W;    r = rg - 1536; }
    else if (rg < 2560) { src = p.bw0_W;    r = rg - 2048; }
    else if (rg < 3328) { src = p.fw1_W;    r = rg - 2560; }
    else if (rg < 4096) { src = p.bw1_W;    r = rg - 3328; }
    else if (rg < 4416) { src = p.act0_W;   r = rg - 4096; }
    else if (rg < 4928) { src = p.act1_W;   r = rg - 4416; }
    else if (rg < 5440) { src = p.dq0_W;    r = rg - 4928; }
    else                { src = p.dq1_W;    r = rg - 5440; }
    const size_t ro = (size_t)r * 1024;
    float4 v;
    if (f32) {
        const float* s = reinterpret_cast<const float*>(src) + ro;
        v = make_float4(s[u], s[256 + u], s[512 + u], s[768 + u]);
    } else {
        const ushort_t* s = reinterpret_cast<const ushort_t*>(src) + ro;
        v = make_float4(bf2f(s[u]), bf2f(s[256 + u]), bf2f(s[512 + u]), bf2f(s[768 + u]));
    }
    p.pkf[(size_t)rg * 256 + u] = v;
}

// ---------------------------------------------------------------------------
// Weight packing — plan B/C (tree full + h-rows only)
// ---------------------------------------------------------------------------
__global__ __launch_bounds__(256) void pack_h_kernel(P p) {
    const bool f32 = (p.flag[0] == 1);
    const int rg = blockIdx.x;
    const int u  = threadIdx.x;
    const void* src; int r;
    if      (rg < 512)  { src = p.tree_W;   r = rg; }
    else if (rg < 768)  { src = p.fw0_W;    r = 256 + rg - 512; }
    else if (rg < 1024) { src = p.bw0_W;    r = 256 + rg - 768; }
    else if (rg < 1280) { src = p.fw1_W;    r = 512 + rg - 1024; }
    else if (rg < 1536) { src = p.bw1_W;    r = 512 + rg - 1280; }
    else if (rg < 1792) { src = p.stack0_W; r = 256 + rg - 1536; }
    else if (rg < 2048) { src = p.stack1_W; r = 256 + rg - 1792; }
    else if (rg < 2304) { src = p.act0_W;   r = 64  + rg - 2048; }
    else if (rg < 2560) { src = p.act1_W;   r = 256 + rg - 2304; }
    else if (rg < 2816) { src = p.dq0_W;    r = 256 + rg - 2560; }
    else                { src = p.dq1_W;    r = 256 + rg - 2816; }
    const size_t ro = (size_t)r * 1024;
    float4 v;
    if (f32) {
        const float* s = reinterpret_cast<const float*>(src) + ro;
        v = make_float4(s[u], s[256 + u], s[512 + u], s[768 + u]);
    } else {
        const ushort_t* s = reinterpret_cast<const ushort_t*>(src) + ro;
        v = make_float4(bf2f(s[u]), bf2f(s[256 + u]), bf2f(s[512 + u]), bf2f(s[768 + u]));
    }
    p.pkf[(size_t)rg * 256 + u] = v;
}

// ---------------------------------------------------------------------------
// Embedding
// ---------------------------------------------------------------------------
template<bool F32>
__device__ void embed_impl(const P& p, float* s_e) {
    const int u   = threadIdx.x;
    const int row = blockIdx.x;

    const int* wid; const int* pid; int rowbase; int which;
    float* out_f = nullptr; ushort_t* out_b = nullptr;
    if (row < BB * TT) {
        wid = p.tree_word_id; pid = p.tree_pos_id; rowbase = row; which = 0;
        out_f = p.tree_e;
    } else if (row < BB * TT + BB * LL) {
        wid = p.token_word_id; pid = p.token_pos_id; rowbase = row - BB * TT; which = 1;
        out_b = p.token_e;
    } else {
        wid = p.deque_word_id; pid = p.deque_pos_id; rowbase = row - BB * TT - BB * LL; which = 2;
        out_b = p.deque_e;
    }

    const int w  = wid[rowbase];
    const int pp = pid[rowbase];
    for (int e = u; e < WDIM + PDIM; e += 256) {
        s_e[e] = (e < WDIM) ? ld1<F32>(p.word_emb, (size_t)w * WDIM + e)
                            : ld1<F32>(p.pos_emb, (size_t)pp * PDIM + (e - WDIM));
    }
    __syncthreads();

    float acc = ld1<F32>(p.wd_b, u);
    for (int r = 0; r < WDIM + PDIM; ++r)
        acc = fmaf(s_e[r], ld1<F32>(p.wd_W, (size_t)r * UU + u), acc);
    acc = fmaxf(acc, 0.f);
    if (which == 0) out_f[(size_t)rowbase * UU + u] = acc;
    else            out_b[(size_t)rowbase * UU + u] = f2bf(acc);
}

__global__ __launch_bounds__(256) void embed_kernel(P p) {
    __shared__ __align__(16) float s_e[384];
    if (p.flag[0] == 1) embed_impl<true>(p, s_e);
    else                embed_impl<false>(p, s_e);
}

// ---------------------------------------------------------------------------
// One LSTM step over packed float4 weights (256 threads).
// ---------------------------------------------------------------------------
template<int R>
__device__ __forceinline__ float lstm_step_f4(const float4* __restrict__ Wp,
                                              const float4 bz,
                                              const float* __restrict__ s_xh,
                                              float& c) {
    float zi = bz.x, zj = bz.y, zf = bz.z, zo = bz.w;
    for (int r0 = 0; r0 < R; r0 += 16) {
        float4 w[16];
        #pragma unroll
        for (int k = 0; k < 16; ++k) w[k] = Wp[(size_t)(r0 + k) * 256];
        __builtin_amdgcn_sched_barrier(0);
        #pragma unroll
        for (int q = 0; q < 4; ++q) {
            const float4 x4 = *reinterpret_cast<const float4*>(s_xh + r0 + 4 * q);
            const float xv[4] = {x4.x, x4.y, x4.z, x4.w};
            #pragma unroll
            for (int j = 0; j < 4; ++j) {
                const float4 wv = w[4 * q + j];
                zi = fmaf(xv[j], wv.x, zi);
                zj = fmaf(xv[j], wv.y, zj);
                zf = fmaf(xv[j], wv.z, zf);
                zo = fmaf(xv[j], wv.w, zo);
            }
        }
    }
    const float nc = c * sigm(zf) + sigm(zi) * tanhf(zj);
    c = nc;
    return tanhf(nc) * sigm(zo);
}

template<bool F32>
__device__ __forceinline__ float4 load_bias4(const void* b, int u) {
    // gates i|j|f|o at cols u, 256+u, 512+u, 768+u; forget bias folded in.
    return make_float4(ld1<F32>(b, u), ld1<F32>(b, 256 + u),
                       ld1<F32>(b, 512 + u) + 1.0f, ld1<F32>(b, 768 + u));
}

__device__ __forceinline__ float4 zx_load(const uint2* __restrict__ zx, size_t n, int u) {
    const uint2 v = zx[n * 256 + u];
    const float2 ij = unp2h(v.x);
    const float2 fo = unp2h(v.y);
    return make_float4(ij.x, ij.y, fo.x, fo.y);
}

// ---------------------------------------------------------------------------
// Full tree (x+h rows), 256 threads — Plan B & fallback
// ---------------------------------------------------------------------------
template<bool F32>
__device__ void run_tree_f4(int b, const P& p, float* smem) {
    const int u = threadIdx.x;
    float* s_x  = smem;          // 256
    float* s_hj = smem + 256;    // 256
    float* s_hk = smem + 512;    // 1024
    float* H = p.H;
    float* C = p.C;
    H[(size_t)b * UU + u] = 0.f;
    C[(size_t)b * UU + u] = 0.f;

    const float4* __restrict__ Wt = p.pkf + u;                 // x rows [0,256)
    const float4* __restrict__ Wh = Wt + (size_t)256 * 256;    // h rows [256,512)
    const float bi = ld1<F32>(p.tree_b, u);
    const float bj = ld1<F32>(p.tree_b, 256 + u);
    const float bo = ld1<F32>(p.tree_b, 512 + u);
    const float bf = ld1<F32>(p.tree_b, 768 + u) + 1.0f;

    for (int i = 0; i < TT; ++i) {
        const int* co = p.children_order + ((size_t)b * TT + i) * KK;
        const int i0 = co[0], i1 = co[1], i2 = co[2], i3 = co[3];
        const float h0 = H[((size_t)i0 * BB + b) * UU + u];
        const float h1 = H[((size_t)i1 * BB + b) * UU + u];
        const float h2 = H[((size_t)i2 * BB + b) * UU + u];
        const float h3 = H[((size_t)i3 * BB + b) * UU + u];
        const float c0 = C[((size_t)i0 * BB + b) * UU + u];
        const float c1 = C[((size_t)i1 * BB + b) * UU + u];
        const float c2 = C[((size_t)i2 * BB + b) * UU + u];
        const float c3 = C[((size_t)i3 * BB + b) * UU + u];
        s_x[u]        = p.tree_e[((size_t)b * TT + i) * UU + u];
        s_hk[u]       = h0;
        s_hk[256 + u] = h1;
        s_hk[512 + u] = h2;
        s_hk[768 + u] = h3;
        s_hj[u]       = h0 + h1 + h2 + h3;
        __syncthreads();

        float zi = bi, zj = bj, zo = bo, fx = bf;
        for (int r0 = 0; r0 < 256; r0 += 16) {        // x rows
            float4 w[16];
            #pragma unroll
            for (int k = 0; k < 16; ++k) w[k] = Wt[(size_t)(r0 + k) * 256];
            __builtin_amdgcn_sched_barrier(0);
            #pragma unroll
            for (int q = 0; q < 4; ++q) {
                const float4 x4 = *reinterpret_cast<const float4*>(s_x + r0 + 4 * q);
                const float xv[4] = {x4.x, x4.y, x4.z, x4.w};
                #pragma unroll
                for (int j = 0; j < 4; ++j) {
                    const float4 wv = w[4 * q + j];
                    zi = fmaf(xv[j], wv.x, zi);
                    zj = fmaf(xv[j], wv.y, zj);
                    zo = fmaf(xv[j], wv.z, zo);
                    fx = fmaf(xv[j], wv.w, fx);
                }
            }
        }
        float f0 = 0.f, f1 = 0.f, f2 = 0.f, f3 = 0.f;
        for (int r0 = 0; r0 < 256; r0 += 16) {        // h rows
            float4 w[16];
            #pragma unroll
            for (int k = 0; k < 16; ++k) w[k] = Wh[(size_t)(r0 + k) * 256];
            __builtin_amdgcn_sched_barrier(0);
            #pragma unroll
            for (int q = 0; q < 4; ++q) {
                const int r = r0 + 4 * q;
                const float4 hj4 = *reinterpret_cast<const float4*>(s_hj + r);
                const float4 a0  = *reinterpret_cast<const float4*>(s_hk + r);
                const float4 a1  = *reinterpret_cast<const float4*>(s_hk + 256 + r);
                const float4 a2  = *reinterpret_cast<const float4*>(s_hk + 512 + r);
                const float4 a3  = *reinterpret_cast<const float4*>(s_hk + 768 + r);
                const float hjv[4] = {hj4.x, hj4.y, hj4.z, hj4.w};
                const float k0[4]  = {a0.x, a0.y, a0.z, a0.w};
                const float k1[4]  = {a1.x, a1.y, a1.z, a1.w};
                const float k2[4]  = {a2.x, a2.y, a2.z, a2.w};
                const float k3[4]  = {a3.x, a3.y, a3.z, a3.w};
                #pragma unroll
                for (int j = 0; j < 4; ++j) {
                    const float4 wv = w[4 * q + j];
                    zi = fmaf(hjv[j], wv.x, zi);
                    zj = fmaf(hjv[j], wv.y, zj);
                    zo = fmaf(hjv[j], wv.z, zo);
                    f0 = fmaf(k0[j], wv.w, f0);
                    f1 = fmaf(k1[j], wv.w, f1);
                    f2 = fmaf(k2[j], wv.w, f2);
                    f3 = fmaf(k3[j], wv.w, f3);
                }
            }
        }
        const float fsum = c0 * sigm(fx + f0) + c1 * sigm(fx + f1)
                         + c2 * sigm(fx + f2) + c3 * sigm(fx + f3);
        const float nc = fsum + sigm(zi) * tanhf(zj);
        const float nh = tanhf(nc) * sigm(zo);
        __syncthreads();
        H[((size_t)(i + 1) * BB + b) * UU + u] = nh;
        C[((size_t)(i + 1) * BB + b) * UU + u] = nc;
    }
}

// ---------------------------------------------------------------------------
// Tree h-only (Plan C): x-part comes from zxT (f32x4 {i,j,o,f+b+1}).
// ---------------------------------------------------------------------------
template<bool F32>
__device__ void run_tree_hc(int b, const P& p, float* smem) {
    const int u = threadIdx.x;
    float* s_hj = smem;          // 256
    float* s_hk = smem + 256;    // 1024
    float* H = p.H;
    float* C = p.C;
    H[(size_t)b * UU + u] = 0.f;
    C[(size_t)b * UU + u] = 0.f;
    const float4* __restrict__ Wh = p.pkf + (size_t)256 * 256 + u;   // tree h rows

    for (int i = 0; i < TT; ++i) {
        const int* co = p.children_order + ((size_t)b * TT + i) * KK;
        const int i0 = co[0], i1 = co[1], i2 = co[2], i3 = co[3];
        const float h0 = H[((size_t)i0 * BB + b) * UU + u];
        const float h1 = H[((size_t)i1 * BB + b) * UU + u];
        const float h2 = H[((size_t)i2 * BB + b) * UU + u];
        const float h3 = H[((size_t)i3 * BB + b) * UU + u];
        const float c0 = C[((size_t)i0 * BB + b) * UU + u];
        const float c1 = C[((size_t)i1 * BB + b) * UU + u];
        const float c2 = C[((size_t)i2 * BB + b) * UU + u];
        const float c3 = C[((size_t)i3 * BB + b) * UU + u];
        s_hk[u]       = h0;
        s_hk[256 + u] = h1;
        s_hk[512 + u] = h2;
        s_hk[768 + u] = h3;
        s_hj[u]       = h0 + h1 + h2 + h3;
        __syncthreads();

        const float4 z0 = p.zxT[((size_t)b * TT + i) * 256 + u];
        float zi = z0.x, zj = z0.y, zo = z0.z, fx = z0.w;
        float f0 = 0.f, f1 = 0.f, f2 = 0.f, f3 = 0.f;
        for (int r0 = 0; r0 < 256; r0 += 16) {
            float4 w[16];
            #pragma unroll
            for (int k = 0; k < 16; ++k) w[k] = Wh[(size_t)(r0 + k) * 256];
            __builtin_amdgcn_sched_barrier(0);
            #pragma unroll
            for (int q = 0; q < 4; ++q) {
                const int r = r0 + 4 * q;
                const float4 hj4 = *reinterpret_cast<const float4*>(s_hj + r);
                const float4 a0  = *reinterpret_cast<const float4*>(s_hk + r);
                const float4 a1  = *reinterpret_cast<const float4*>(s_hk + 256 + r);
                const float4 a2  = *reinterpret_cast<const float4*>(s_hk + 512 + r);
                const float4 a3  = *reinterpret_cast<const float4*>(s_hk + 768 + r);
                const float hjv[4] = {hj4.x, hj4.y, hj4.z, hj4.w};
                const float k0[4]  = {a0.x, a0.y, a0.z, a0.w};
                const float k1[4]  = {a1.x, a1.y, a1.z, a1.w};
                const float k2[4]  = {a2.x, a2.y, a2.z, a2.w};
                const float k3[4]  = {a3.x, a3.y, a3.z, a3.w};
                #pragma unroll
                for (int j = 0; j < 4; ++j) {
                    const float4 wv = w[4 * q + j];
                    zi = fmaf(hjv[j], wv.x, zi);
                    zj = fmaf(hjv[j], wv.y, zj);
                    zo = fmaf(hjv[j], wv.z, zo);
                    f0 = fmaf(k0[j], wv.w, f0);
                    f1 = fmaf(k1[j], wv.w, f1);
                    f2 = fmaf(k2[j], wv.w, f2);
                    f3 = fmaf(k3[j], wv.w, f3);
                }
            }
        }
        const float fsum = c0 * sigm(fx + f0) + c1 * sigm(fx + f1)
                         + c2 * sigm(fx + f2) + c3 * sigm(fx + f3);
        const float nc = fsum + sigm(zi) * tanhf(zj);
        const float nh = tanhf(nc) * sigm(zo);
        __syncthreads();
        H[((size_t)(i + 1) * BB + b) * UU + u] = nh;
        C[((size_t)(i + 1) * BB + b) * UU + u] = nc;
    }
}

// ===========================================================================
// FALLBACK (round-2) fused chains
// ===========================================================================
template<bool F32>
__device__ void run_token_l0_f4(int b, const P& p, float* smem, bool is_bw) {
    const int u = threadIdx.x;
    float* s_xh = smem;
    const int len = p.token_length[b];
    const float4* __restrict__ Wp = p.pkf + (size_t)(is_bw ? OFF_BW0 : OFF_FW0) * 256 + u;
    const float4 bz = load_bias4<F32>(is_bw ? p.bw0_b : p.fw0_b, u);

    float c0 = 0.f;
    s_xh[256 + u] = 0.f;
    for (int t = 0; t < len; ++t) {
        const int row = is_bw ? (len - 1 - t) : t;
        s_xh[u] = bf2f(p.token_e[((size_t)b * LL + row) * UU + u]);
        __syncthreads();
        const float nh = lstm_step_f4<512>(Wp, bz, s_xh, c0);
        p.x1[((size_t)b * LL + row) * 512 + (is_bw ? 256 : 0) + u] = f2bf(nh);
        __syncthreads();
        s_xh[256 + u] = nh;
    }
}

template<bool F32>
__device__ void run_act_dq_f4(int b, const P& p, float* smem) {
    const int u = threadIdx.x;
    float* s_xh0 = smem;
    float* s_xh1 = smem + 512;

    {
        const int len = p.history_action_length[b];
        const float4* __restrict__ W0 = p.pkf + (size_t)OFF_ACT0 * 256 + u;
        const float4* __restrict__ W1 = p.pkf + (size_t)OFF_ACT1 * 256 + u;
        const float4 bz0 = load_bias4<F32>(p.act0_b, u);
        const float4 bz1 = load_bias4<F32>(p.act1_b, u);
        float ca0 = 0.f, ca1 = 0.f, h1last = 0.f;
        s_xh0[ADIM + u] = 0.f;
        s_xh1[256 + u]  = 0.f;
        for (int t = 0; t < len; ++t) {
            const int aid = p.history_action_id[b * AA + t];
            if (u < ADIM) s_xh0[u] = ld1<F32>(p.act_emb, (size_t)aid * ADIM + u);
            __syncthreads();
            const float nh0 = lstm_step_f4<320>(W0, bz0, s_xh0, ca0);
            __syncthreads();
            s_xh0[ADIM + u] = nh0;
            s_xh1[u]        = nh0;
            __syncthreads();
            const float nh1 = lstm_step_f4<512>(W1, bz1, s_xh1, ca1);
            __syncthreads();
            s_xh1[256 + u] = nh1;
            h1last = nh1;
        }
        p.act_h[b * UU + u] = h1last;
    }
    __syncthreads();
    {
        const int len = p.deque_length[b];
        const float4* __restrict__ W0 = p.pkf + (size_t)OFF_DQ0 * 256 + u;
        const float4* __restrict__ W1 = p.pkf + (size_t)OFF_DQ1 * 256 + u;
        const float4 bz0 = load_bias4<F32>(p.dq0_b, u);
        const float4 bz1 = load_bias4<F32>(p.dq1_b, u);
        float cd0 = 0.f, cd1 = 0.f, h1last = 0.f;
        s_xh0[256 + u] = 0.f;
        s_xh1[256 + u] = 0.f;
        for (int t = 0; t < len; ++t) {
            s_xh0[u] = bf2f(p.deque_e[((size_t)b * DQN + t) * UU + u]);
            __syncthreads();
            const float nh0 = lstm_step_f4<512>(W0, bz0, s_xh0, cd0);
            __syncthreads();
            s_xh0[256 + u] = nh0;
            s_xh1[u]       = nh0;
            __syncthreads();
            const float nh1 = lstm_step_f4<512>(W1, bz1, s_xh1, cd1);
            __syncthreads();
            s_xh1[256 + u] = nh1;
            h1last = nh1;
        }
        p.dq_h[b * UU + u] = h1last;
    }
}

__global__ __launch_bounds__(256) void phase1_fb_kernel(P p) {
    __shared__ __align__(16) float smem[1536];
    const bool f32 = (p.flag[0] == 1);
    const int chain = blockIdx.x & 3;
    const int b     = blockIdx.x >> 2;
    if (f32) {
        if (chain == 0)      run_tree_f4<true>(b, p, smem);
        else if (chain == 1) run_token_l0_f4<true>(b, p, smem, false);
        else if (chain == 2) run_token_l0_f4<true>(b, p, smem, true);
        else                 run_act_dq_f4<true>(b, p, smem);
    } else {
        if (chain == 0)      run_tree_f4<false>(b, p, smem);
        else if (chain == 1) run_token_l0_f4<false>(b, p, smem, false);
        else if (chain == 2) run_token_l0_f4<false>(b, p, smem, true);
        else                 run_act_dq_f4<false>(b, p, smem);
    }
}

template<bool F32>
__device__ void run_stack_f4(int b, const P& p, float* smem) {
    const int u = threadIdx.x;
    float* s_xh0 = smem;
    float* s_xh1 = smem + 512;
    const int len = p.stack_length[b];
    const float4* __restrict__ W0 = p.pkf + (size_t)OFF_S0 * 256 + u;
    const float4* __restrict__ W1 = p.pkf + (size_t)OFF_S1 * 256 + u;
    const float4 bz0 = load_bias4<F32>(p.stack0_b, u);
    const float4 bz1 = load_bias4<F32>(p.stack1_b, u);
    float cs0 = 0.f, cs1 = 0.f, h1last = 0.f;
    s_xh0[256 + u] = 0.f;
    s_xh1[256 + u] = 0.f;
    for (int t = 0; t < len; ++t) {
        const int so = p.stack_order[b * SS + t];
        s_xh0[u] = p.H[((size_t)so * BB + b) * UU + u];
        __syncthreads();
        const float nh0 = lstm_step_f4<512>(W0, bz0, s_xh0, cs0);
        __syncthreads();
        s_xh0[256 + u] = nh0;
        s_xh1[u]       = nh0;
        __syncthreads();
        const float nh1 = lstm_step_f4<512>(W1, bz1, s_xh1, cs1);
        __syncthreads();
        s_xh1[256 + u] = nh1;
        h1last = nh1;
    }
    p.stack_h[b * UU + u] = h1last;
}

template<bool F32>
__device__ void run_token_l1_f4(int b, const P& p, float* smem, bool is_bw) {
    const int u = threadIdx.x;
    float* s_xh = smem;
    const int len  = p.token_length[b];
    const int btop = p.buff_top_id[b];
    const float4* __restrict__ Wp = p.pkf + (size_t)(is_bw ? OFF_BW1 : OFF_FW1) * 256 + u;
    const float4 bz = load_bias4<F32>(is_bw ? p.bw1_b : p.fw1_b, u);

    float c1 = 0.f, hlast = 0.f;
    s_xh[512 + u] = 0.f;
    for (int t = 0; t < len; ++t) {
        const int row = is_bw ? (len - 1 - t) : t;
        const ushort_t* xr = p.x1 + ((size_t)b * LL + row) * 512;
        s_xh[u]       = bf2f(xr[u]);
        s_xh[256 + u] = bf2f(xr[256 + u]);
        __syncthreads();
        const float nh = lstm_step_f4<768>(Wp, bz, s_xh, c1);
        if (!is_bw) {
            if (t == btop) p.fw_top[b * UU + u] = nh;
        } else {
            if (t == 0)              p.bw_bottom[b * UU + u] = nh;
            if (t == len - 1 - btop) p.bw_top[b * UU + u]    = nh;
        }
        __syncthreads();
        s_xh[512 + u] = nh;
        hlast = nh;
    }
    if (!is_bw) p.fw1_h[b * UU + u] = hlast;
}

__global__ __launch_bounds__(256) void phase2_fb_kernel(P p) {
    __shared__ __align__(16) float smem[1024];
    const bool f32 = (p.flag[0] == 1);
    const int chain = blockIdx.x % 3;
    const int b     = blockIdx.x / 3;
    if (f32) {
        if (chain == 0)      run_stack_f4<true>(b, p, smem);
        else if (chain == 1) run_token_l1_f4<true>(b, p, smem, false);
        else                 run_token_l1_f4<true>(b, p, smem, true);
    } else {
        if (chain == 0)      run_stack_f4<false>(b, p, smem);
        else if (chain == 1) run_token_l1_f4<false>(b, p, smem, false);
        else                 run_token_l1_f4<false>(b, p, smem, true);
    }
}

// ===========================================================================
// x-part precompute (xpre, 32-row tiles / 32 KB LDS)
// ===========================================================================
template<bool F32, int R>
__device__ void xpre_compute(const void* __restrict__ W, const void* __restrict__ bias,
                             uint2* __restrict__ zx, int n0,
                             const float* __restrict__ s_xf, const ushort_t* __restrict__ s_xb) {
    const int u = threadIdx.x;
    const float4 bz = load_bias4<F32>(bias, u);
    for (int c = 0; c < 32; c += 8) {
        float4 acc[8];
        #pragma unroll
        for (int n = 0; n < 8; ++n) acc[n] = bz;
        for (int r0 = 0; r0 < R; r0 += 8) {
            float4 w[8];
            #pragma unroll
            for (int k = 0; k < 8; ++k) {
                const size_t ro = (size_t)(r0 + k) * 1024;
                w[k] = make_float4(ld1<F32>(W, ro + u),
                                   ld1<F32>(W, ro + 256 + u),
                                   ld1<F32>(W, ro + 512 + u),
                                   ld1<F32>(W, ro + 768 + u));
            }
            #pragma unroll
            for (int n = 0; n < 8; ++n) {
                float xv[8];
                #pragma unroll
                for (int k = 0; k < 8; ++k)
                    xv[k] = (R == 512) ? bf2f(s_xb[(size_t)(c + n) * 512 + r0 + k])
                                       : s_xf[(size_t)(c + n) * R + r0 + k];
                #pragma unroll
                for (int k = 0; k < 8; ++k) {
                    acc[n].x = fmaf(xv[k], w[k].x, acc[n].x);
                    acc[n].y = fmaf(xv[k], w[k].y, acc[n].y);
                    acc[n].z = fmaf(xv[k], w[k].z, acc[n].z);
                    acc[n].w = fmaf(xv[k], w[k].w, acc[n].w);
                }
            }
        }
        #pragma unroll
        for (int n = 0; n < 8; ++n) {
            uint2 v;
            v.x = pack2h(acc[n].x, acc[n].y);
            v.y = pack2h(acc[n].z, acc[n].w);
            zx[(size_t)(n0 + c + n) * 256 + u] = v;
        }
    }
}

// Tree variant: f32x4 output, gate order i|j|o|f, forget bias on .w.
template<bool F32>
__device__ void xpre_tree_compute(const void* __restrict__ W, const void* __restrict__ bias,
                                  float4* __restrict__ zxT, int n0,
                                  const float* __restrict__ s_xf) {
    const int u = threadIdx.x;
    const float4 bz = make_float4(ld1<F32>(bias, u), ld1<F32>(bias, 256 + u),
                                  ld1<F32>(bias, 512 + u),
                                  ld1<F32>(bias, 768 + u) + 1.0f);
    for (int c = 0; c < 32; c += 8) {
        float4 acc[8];
        #pragma unroll
        for (int n = 0; n < 8; ++n) acc[n] = bz;
        for (int r0 = 0; r0 < 256; r0 += 8) {
            float4 w[8];
            #pragma unroll
            for (int k = 0; k < 8; ++k) {
                const size_t ro = (size_t)(r0 + k) * 1024;
                w[k] = make_float4(ld1<F32>(W, ro + u),
                                   ld1<F32>(W, ro + 256 + u),
                                   ld1<F32>(W, ro + 512 + u),
                                   ld1<F32>(W, ro + 768 + u));
            }
            #pragma unroll
            for (int n = 0; n < 8; ++n) {
                #pragma unroll
                for (int k = 0; k < 8; ++k) {
                    const float xv = s_xf[(size_t)(c + n) * 256 + r0 + k];
                    acc[n].x = fmaf(xv, w[k].x, acc[n].x);
                    acc[n].y = fmaf(xv, w[k].y, acc[n].y);
                    acc[n].z = fmaf(xv, w[k].z, acc[n].z);
                    acc[n].w = fmaf(xv, w[k].w, acc[n].w);
                }
            }
        }
        #pragma unroll
        for (int n = 0; n < 8; ++n)
            zxT[(size_t)(n0 + c + n) * 256 + u] = acc[n];
    }
}

template<bool F32, int STAGE>
__device__ void xpre_impl(const P& p, char* s_raw) {
    float*    s_xf = reinterpret_cast<float*>(s_raw);
    ushort_t* s_xb = reinterpret_cast<ushort_t*>(s_raw);
    const int blk = blockIdx.x;
    const int tid = threadIdx.x;

    const void* W; const void* bias; uint2* zx = nullptr; int R; int kind; int n0;
    if (STAGE == 0) {
        if (blk < 256)      { W=p.fw0_W;  bias=p.fw0_b;  zx=p.zxA; R=256; kind=0; n0=blk*32; }
        else if (blk < 512) { W=p.bw0_W;  bias=p.bw0_b;  zx=p.zxB; R=256; kind=0; n0=(blk-256)*32; }
        else if (blk < 640) { W=p.act0_W; bias=p.act0_b; zx=p.zxC; R=64;  kind=3; n0=(blk-512)*32; }
        else if (blk < 704) { W=p.dq0_W;  bias=p.dq0_b;  zx=p.zxD; R=256; kind=1; n0=(blk-640)*32; }
        else                { W=p.tree_W; bias=p.tree_b; R=256;    kind=8; n0=(blk-704)*32; }
    } else if (STAGE == 1) {
        if (blk < 256)      { W=p.fw1_W;    bias=p.fw1_b;    zx=p.zxA; R=512; kind=2; n0=blk*32; }
        else if (blk < 512) { W=p.bw1_W;    bias=p.bw1_b;    zx=p.zxB; R=512; kind=2; n0=(blk-256)*32; }
        else if (blk < 640) { W=p.stack0_W; bias=p.stack0_b; zx=p.zxS; R=256; kind=4; n0=(blk-512)*32; }
        else if (blk < 768) { W=p.act1_W;   bias=p.act1_b;   zx=p.zxC; R=256; kind=5; n0=(blk-640)*32; }
        else                { W=p.dq1_W;    bias=p.dq1_b;    zx=p.zxD; R=256; kind=6; n0=(blk-768)*32; }
    } else {
        W=p.stack1_W; bias=p.stack1_b; zx=p.zxS; R=256; kind=7; n0=blk*32;
    }

    // stage the 32-row x tile into LDS (max 32 KB)
    if (kind == 0 || kind == 1) {                 // bf16 linear, R=256
        const ushort_t* src = (kind == 0 ? p.token_e : p.deque_e) + (size_t)n0 * 256;
        for (int i = tid; i < 32 * 256; i += 256) s_xf[i] = bf2f(src[i]);
    } else if (kind == 2) {                       // x1 bf16, R=512 (kept bf16 in LDS)
        const ushort_t* src = p.x1 + (size_t)n0 * 512;
        for (int i = tid; i < 32 * 512; i += 256) s_xb[i] = src[i];
    } else if (kind == 3) {                       // act_emb gather, R=64
        const int b = n0 >> 6, t0 = n0 & 63;
        for (int i = tid; i < 32 * 64; i += 256) {
            const int t = t0 + (i >> 6), r = i & 63;
            int aid = p.history_action_id[b * AA + t];
            aid = aid < 0 ? 0 : (aid > NAOUT - 1 ? NAOUT - 1 : aid);   // clamp
            s_xf[i] = ld1<F32>(p.act_emb, (size_t)aid * ADIM + r);
        }
    } else if (kind == 4) {                       // H gather (stack0), R=256
        const int b = n0 >> 6, t0 = n0 & 63;
        for (int i = tid; i < 32 * 256; i += 256) {
            const int t = t0 + (i >> 8), r = i & 255;
            int so = p.stack_order[b * SS + t];
            so = so < 0 ? 0 : (so > TT ? TT : so);                     // clamp
            s_xf[i] = p.H[((size_t)so * BB + b) * UU + r];
        }
    } else if (kind == 8) {                       // tree_e linear f32, R=256
        const float* src = p.tree_e + (size_t)n0 * 256;
        for (int i = tid; i < 32 * 256; i += 256) s_xf[i] = src[i];
    } else {                                      // f32 linear h0-seqs, R=256
        const float* src = (kind == 5 ? p.a0_seq : kind == 6 ? p.d0_seq : p.s0_seq)
                         + (size_t)n0 * 256;
        for (int i = tid; i < 32 * 256; i += 256) s_xf[i] = src[i];
    }
    __syncthreads();

    if (kind == 8)     xpre_tree_compute<F32>(W, bias, p.zxT, n0, s_xf);
    else if (R == 512) xpre_compute<F32, 512>(W, bias, zx, n0, s_xf, s_xb);
    else if (R == 256) xpre_compute<F32, 256>(W, bias, zx, n0, s_xf, s_xb);
    else               xpre_compute<F32, 64 >(W, bias, zx, n0, s_xf, s_xb);
}

__global__ __launch_bounds__(256) void xpre0_kernel(P p) {
    __shared__ __align__(16) char s_raw[32768];
    if (p.flag[0] == 1) xpre_impl<true, 0>(p, s_raw);
    else                xpre_impl<false, 0>(p, s_raw);
}
__global__ __launch_bounds__(256) void xpre1_kernel(P p) {
    __shared__ __align__(16) char s_raw[32768];
    if (p.flag[0] == 1) xpre_impl<true, 1>(p, s_raw);
    else                xpre_impl<false, 1>(p, s_raw);
}
__global__ __launch_bounds__(256) void xpre2_kernel(P p) {
    __shared__ __align__(16) char s_raw[32768];
    if (p.flag[0] == 1) xpre_impl<true, 2>(p, s_raw);
    else                xpre_impl<false, 2>(p, s_raw);
}

// ===========================================================================
// Chain step helpers (256-thread, h-only)
// ===========================================================================
template<bool F32>
__device__ void chain_token_l0(int b, const P& p, float* s_h, bool bw) {
    const int u = threadIdx.x;
    const int len = p.token_length[b];
    const float4* __restrict__ Wh = p.pkf + (size_t)(bw ? PKH_BW0 : PKH_FW0) * 256 + u;
    const uint2* zx = bw ? p.zxB : p.zxA;
    float c = 0.f;
    s_h[u] = 0.f;
    __syncthreads();
    for (int t = 0; t < len; ++t) {
        const int row = bw ? (len - 1 - t) : t;
        const float4 bz = zx_load(zx, (size_t)b * LL + row, u);
        const float nh = lstm_step_f4<256>(Wh, bz, s_h, c);
        p.x1[((size_t)b * LL + row) * 512 + (bw ? 256 : 0) + u] = f2bf(nh);
        __syncthreads();
        s_h[u] = nh;
        __syncthreads();
    }
}

template<bool F32>
__device__ void chain_act0(int b, const P& p, float* s_h) {
    const int u = threadIdx.x;
    const int len = p.history_action_length[b];
    const float4* __restrict__ Wh = p.pkf + (size_t)PKH_ACT0 * 256 + u;
    float c = 0.f;
    s_h[u] = 0.f;
    __syncthreads();
    for (int t = 0; t < len; ++t) {
        const float4 bz = zx_load(p.zxC, (size_t)b * AA + t, u);
        const float nh = lstm_step_f4<256>(Wh, bz, s_h, c);
        p.a0_seq[((size_t)b * AA + t) * UU + u] = nh;
        __syncthreads();
        s_h[u] = nh;
        __syncthreads();
    }
}

template<bool F32>
__device__ void chain_dq0(int b, const P& p, float* s_h) {
    const int u = threadIdx.x;
    const int len = p.deque_length[b];
    const float4* __restrict__ Wh = p.pkf + (size_t)PKH_DQ0 * 256 + u;
    float c = 0.f;
    s_h[u] = 0.f;
    __syncthreads();
    for (int t = 0; t < len; ++t) {
        const float4 bz = zx_load(p.zxD, (size_t)b * DQN + t, u);
        const float nh = lstm_step_f4<256>(Wh, bz, s_h, c);
        p.d0_seq[((size_t)b * DQN + t) * UU + u] = nh;
        __syncthreads();
        s_h[u] = nh;
        __syncthreads();
    }
}

template<bool F32>
__device__ void chain_fw1(int b, const P& p, float* s_h) {
    const int u = threadIdx.x;
    const int len  = p.token_length[b];
    const int btop = p.buff_top_id[b];
    const float4* __restrict__ Wh = p.pkf + (size_t)PKH_FW1 * 256 + u;
    float c = 0.f, hlast = 0.f;
    s_h[u] = 0.f;
    __syncthreads();
    for (int t = 0; t < len; ++t) {
        const float4 bz = zx_load(p.zxA, (size_t)b * LL + t, u);
        const float nh = lstm_step_f4<256>(Wh, bz, s_h, c);
        if (t == btop) p.fw_top[b * UU + u] = nh;
        __syncthreads();
        s_h[u] = nh;
        __syncthreads();
        hlast = nh;
    }
    p.fw1_h[b * UU + u] = hlast;
}

template<bool F32>
__device__ void chain_bw1(int b, const P& p, float* s_h) {
    const int u = threadIdx.x;
    const int len  = p.token_length[b];
    const int btop = p.buff_top_id[b];
    const float4* __restrict__ Wh = p.pkf + (size_t)PKH_BW1 * 256 + u;
    float c = 0.f;
    s_h[u] = 0.f;
    __syncthreads();
    for (int t = 0; t < len; ++t) {
        const int row = len - 1 - t;
        const float4 bz = zx_load(p.zxB, (size_t)b * LL + row, u);
        const float nh = lstm_step_f4<256>(Wh, bz, s_h, c);
        if (t == 0)              p.bw_bottom[b * UU + u] = nh;
        if (t == len - 1 - btop) p.bw_top[b * UU + u]    = nh;
        __syncthreads();
        s_h[u] = nh;
        __syncthreads();
    }
}

template<bool F32>
__device__ void chain_stack0(int b, const P& p, float* s_h) {
    const int u = threadIdx.x;
    const int len = p.stack_length[b];
    const float4* __restrict__ Wh = p.pkf + (size_t)PKH_S0 * 256 + u;
    float c = 0.f;
    s_h[u] = 0.f;
    __syncthreads();
    for (int t = 0; t < len; ++t) {
        const float4 bz = zx_load(p.zxS, (size_t)b * SS + t, u);
        const float nh = lstm_step_f4<256>(Wh, bz, s_h, c);
        p.s0_seq[((size_t)b * SS + t) * UU + u] = nh;
        __syncthreads();
        s_h[u] = nh;
        __syncthreads();
    }
}

template<bool F32>
__device__ void chain_act1(int b, const P& p, float* s_h) {
    const int u = threadIdx.x;
    const int len = p.history_action_length[b];
    const float4* __restrict__ Wh = p.pkf + (size_t)PKH_ACT1 * 256 + u;
    float c = 0.f, hlast = 0.f;
    s_h[u] = 0.f;
    __syncthreads();
    for (int t = 0; t < len; ++t) {
        const float4 bz = zx_load(p.zxC, (size_t)b * AA + t, u);
        const float nh = lstm_step_f4<256>(Wh, bz, s_h, c);
        __syncthreads();
        s_h[u] = nh;
        __syncthreads();
        hlast = nh;
    }
    p.act_h[b * UU + u] = hlast;
}

template<bool F32>
__device__ void chain_dq1(int b, const P& p, float* s_h) {
    const int u = threadIdx.x;
    const int len = p.deque_length[b];
    const float4* __restrict__ Wh = p.pkf + (size_t)PKH_DQ1 * 256 + u;
    float c = 0.f, hlast = 0.f;
    s_h[u] = 0.f;
    __syncthreads();
    for (int t = 0; t < len; ++t) {
        const float4 bz = zx_load(p.zxD, (size_t)b * DQN + t, u);
        const float nh = lstm_step_f4<256>(Wh, bz, s_h, c);
        __syncthreads();
        s_h[u] = nh;
        __syncthreads();
        hlast = nh;
    }
    p.dq_h[b * UU + u] = hlast;
}

// ---------------------------------------------------------------------------
// Plan-B phase kernels (round-4 structure: chain = blockIdx>>6)
// ---------------------------------------------------------------------------
template<bool F32>
__device__ void p1b_impl(const P& p, float* smem) {
    const int chain = blockIdx.x >> 6;
    const int b     = blockIdx.x & 63;
    if (chain == 0)      run_tree_f4<F32>(b, p, smem);
    else if (chain == 1) chain_token_l0<F32>(b, p, smem, false);
    else if (chain == 2) chain_token_l0<F32>(b, p, smem, true);
    else if (chain == 3) chain_act0<F32>(b, p, smem);
    else                 chain_dq0<F32>(b, p, smem);
}

__global__ __launch_bounds__(256) void p1b_kernel(P p) {
    __shared__ __align__(16) float smem[1536];
    if (p.flag[0] == 1) p1b_impl<true>(p, smem);
    else                p1b_impl<false>(p, smem);
}

template<bool F32>
__device__ void p2b_impl(const P& p, float* smem) {
    const int chain = blockIdx.x >> 6;
    const int b     = blockIdx.x & 63;
    if (chain == 0)      chain_fw1<F32>(b, p, smem);
    else if (chain == 1) chain_bw1<F32>(b, p, smem);
    else if (chain == 2) chain_stack0<F32>(b, p, smem);
    else if (chain == 3) chain_act1<F32>(b, p, smem);
    else                 chain_dq1<F32>(b, p, smem);
}

__global__ __launch_bounds__(256) void p2b_kernel(P p) {
    __shared__ __align__(16) float smem[256];
    if (p.flag[0] == 1) p2b_impl<true>(p, smem);
    else                p2b_impl<false>(p, smem);
}

// ---------------------------------------------------------------------------
// Plan-C phase kernels — XCD-pinned: slot = blockIdx & 7 selects the chain,
// so each XCD's L2 holds exactly one 1 MB weight pack (heuristic %8 mapping).
// 512 blocks launched; j = blockIdx >> 3 in [0,64).
// ---------------------------------------------------------------------------
template<bool F32>
__device__ void p1c_impl(const P& p, float* smem) {
    const int s = blockIdx.x & 7;
    const int j = blockIdx.x >> 3;
    if (s == 0 || s == 5) {              // tree on XCD 0 and 5
        if (j >= 32) return;
        run_tree_hc<F32>((s == 5 ? 32 : 0) + j, p, smem);
    } else if (s == 1 || s == 6) {       // fw0
        if (j >= 32) return;
        chain_token_l0<F32>((s == 6 ? 32 : 0) + j, p, smem, false);
    } else if (s == 2 || s == 7) {       // bw0
        if (j >= 32) return;
        chain_token_l0<F32>((s == 7 ? 32 : 0) + j, p, smem, true);
    } else if (s == 3) {                 // act0
        chain_act0<F32>(j, p, smem);
    } else {                             // s == 4: dq0
        chain_dq0<F32>(j, p, smem);
    }
}

__global__ __launch_bounds__(256) void p1c_kernel(P p) {
    __shared__ __align__(16) float smem[1280];
    if (p.flag[0] == 1) p1c_impl<true>(p, smem);
    else                p1c_impl<false>(p, smem);
}

template<bool F32>
__device__ void p2c_impl(const P& p, float* smem) {
    const int s = blockIdx.x & 7;
    const int j = blockIdx.x >> 3;
    if (s == 0 || s == 5) {              // fw1
        if (j >= 32) return;
        chain_fw1<F32>((s == 5 ? 32 : 0) + j, p, smem);
    } else if (s == 1 || s == 6) {       // bw1
        if (j >= 32) return;
        chain_bw1<F32>((s == 6 ? 32 : 0) + j, p, smem);
    } else if (s == 2 || s == 7) {       // stack0
        if (j >= 32) return;
        chain_stack0<F32>((s == 7 ? 32 : 0) + j, p, smem);
    } else if (s == 3) {                 // act1
        chain_act1<F32>(j, p, smem);
    } else {                             // s == 4: dq1
        chain_dq1<F32>(j, p, smem);
    }
}

__global__ __launch_bounds__(256) void p2c_kernel(P p) {
    __shared__ __align__(16) float smem[256];
    if (p.flag[0] == 1) p2c_impl<true>(p, smem);
    else                p2c_impl<false>(p, smem);
}

// ---------------------------------------------------------------------------
// Phase 3: stack layer 1 (shared by B and C)
// ---------------------------------------------------------------------------
template<bool F32>
__device__ void p3_impl(const P& p, float* smem) {
    const int b = blockIdx.x;
    const int u = threadIdx.x;
    const int len = p.stack_length[b];
    const float4* __restrict__ Wh = p.pkf + (size_t)PKH_S1 * 256 + u;
    float c = 0.f, hlast = 0.f;
    smem[u] = 0.f;
    __syncthreads();
    for (int t = 0; t < len; ++t) {
        const float4 bz = zx_load(p.zxS, (size_t)b * SS + t, u);
        const float nh = lstm_step_f4<256>(Wh, bz, smem, c);
        __syncthreads();
        smem[u] = nh;
        __syncthreads();
        hlast = nh;
    }
    p.stack_h[b * UU + u] = hlast;
}

__global__ __launch_bounds__(256) void p3_kernel(P p) {
    __shared__ __align__(16) float smem[256];
    if (p.flag[0] == 1) p3_impl<true>(p, smem);
    else                p3_impl<false>(p, smem);
}

// ---------------------------------------------------------------------------
// Final + pipeline tracers
// ---------------------------------------------------------------------------
template<bool F32>
__device__ __forceinline__ void st_out(void* out, int i, float v) {
    if constexpr (F32) reinterpret_cast<float*>(out)[i] = v;
    else               reinterpret_cast<__hip_bfloat16*>(out)[i] = __float2bfloat16(v);
}

template<bool F32>
__device__ void final_impl(const P& p, void* out, float* s_f) {
    const int b = blockIdx.x;
    const int u = threadIdx.x;
    s_f[u]        = p.stack_h[b * UU + u];
    s_f[256 + u]  = p.fw1_h[b * UU + u] - p.fw_top[b * UU + u];
    s_f[512 + u]  = p.bw_top[b * UU + u] - p.bw_bottom[b * UU + u];
    s_f[768 + u]  = p.act_h[b * UU + u];
    s_f[1024 + u] = p.dq_h[b * UU + u];
    __syncthreads();
    if (u < NAOUT) {
        float acc = ld1<F32>(p.fin_b, u);
        for (int r = 0; r < 1280; ++r)
            acc = fmaf(s_f[r], ld1<F32>(p.fin_W, (size_t)r * NAOUT + u), acc);
        acc = fmaxf(acc, 0.f);
        st_out<F32>(out, b * NAOUT + u, acc);
    }
    if (b == 0 && u == 0) {
        const uint_t POIS = 0xAAAAAAAAu;
        const uint_t* te = reinterpret_cast<const uint_t*>(p.tree_e);
        const uint_t* x1 = reinterpret_cast<const uint_t*>(p.x1);
        const uint_t* sh = reinterpret_cast<const uint_t*>(p.stack_h);
        bool te_p = true, x1_p = true;
        for (int i = 0; i < 8; ++i) { te_p &= (te[i] == POIS); x1_p &= (x1[i] == POIS); }
        bool sh_p = (sh[0] == POIS) && (sh[1] == POIS);
        float sent = 0.f;
        if (te_p)      sent = 3000.f;
        else if (x1_p) sent = 4000.f;
        else if (sh_p) sent = 5000.f;
        else if (*reinterpret_cast<const uint_t*>(p.flag) == POIS) sent = 6000.f;
        if (sent > 0.f) st_out<F32>(out, 0, sent);
    }
}

__global__ __launch_bounds__(256) void final_kernel(P p, void* out) {
    __shared__ __align__(16) float s_f[1280];
    if (p.flag[0] == 1) final_impl<true>(p, out, s_f);
    else                final_impl<false>(p, out, s_f);
}

// ---------------------------------------------------------------------------
extern "C" void kernel_launch(void* const* d_in, const int* in_sizes, int n_in,
                              void* d_out, int out_size, void* d_ws, size_t ws_size,
                              hipStream_t stream) {
    if (n_in != 43) {
        sentinel_kernel<<<1, 64, 0, stream>>>(d_out, 9000.f + (float)n_in);
        return;
    }
    if (out_size != NAOUT * BB) {
        sentinel_kernel<<<1, 64, 0, stream>>>(d_out, 8000.f);
        return;
    }

    P p;
    p.tree_word_id          = (const int*)d_in[0];
    p.tree_pos_id           = (const int*)d_in[1];
    p.token_word_id         = (const int*)d_in[2];
    p.token_pos_id          = (const int*)d_in[3];
    p.history_action_id     = (const int*)d_in[4];
    p.buff_top_id           = (const int*)d_in[5];
    p.deque_word_id         = (const int*)d_in[6];
    p.deque_pos_id          = (const int*)d_in[7];
    p.deque_length          = (const int*)d_in[8];
    p.children_order        = (const int*)d_in[9];
    p.stack_order           = (const int*)d_in[10];
    p.stack_length          = (const int*)d_in[11];
    p.token_length          = (const int*)d_in[12];
    p.history_action_length = (const int*)d_in[13];
    p.word_emb = d_in[14];
    p.pos_emb  = d_in[15];
    p.act_emb  = d_in[16];
    p.wd_W     = d_in[17];
    p.wd_b     = d_in[18];
    p.tree_W   = d_in[19];
    p.tree_b   = d_in[20];
    p.stack0_W = d_in[21];
    p.stack0_b = d_in[22];
    p.stack1_W = d_in[23];
    p.stack1_b = d_in[24];
    p.fw0_W    = d_in[25];
    p.fw0_b    = d_in[26];
    p.bw0_W    = d_in[27];
    p.bw0_b    = d_in[28];
    p.fw1_W    = d_in[29];
    p.fw1_b    = d_in[30];
    p.bw1_W    = d_in[31];
    p.bw1_b    = d_in[32];
    p.act0_W   = d_in[33];
    p.act0_b   = d_in[34];
    p.act1_W   = d_in[35];
    p.act1_b   = d_in[36];
    p.dq0_W    = d_in[37];
    p.dq0_b    = d_in[38];
    p.dq1_W    = d_in[39];
    p.dq1_b    = d_in[40];
    p.fin_W    = d_in[41];
    p.fin_b    = d_in[42];

    char* base = (char*)d_ws;

    // ---- Common (B/C) layout; zxT appended for Plan C (~144 MiB total) ----
    size_t off = 0;
    p.flag = (int*)(base + off);           off += 256;
    p.stack_h   = (float*)(base + off);    off += (size_t)BB * UU * 4;
    p.fw1_h     = (float*)(base + off);    off += (size_t)BB * UU * 4;
    p.fw_top    = (float*)(base + off);    off += (size_t)BB * UU * 4;
    p.bw_top    = (float*)(base + off);    off += (size_t)BB * UU * 4;
    p.bw_bottom = (float*)(base + off);    off += (size_t)BB * UU * 4;
    p.act_h     = (float*)(base + off);    off += (size_t)BB * UU * 4;
    p.dq_h      = (float*)(base + off);    off += (size_t)BB * UU * 4;
    p.tree_e  = (float*)(base + off);      off += (size_t)BB * TT * UU * 4;
    p.token_e = (ushort_t*)(base + off);   off += (size_t)BB * LL * UU * 2;
    p.deque_e = (ushort_t*)(base + off);   off += (size_t)BB * DQN * UU * 2;
    p.x1      = (ushort_t*)(base + off);   off += (size_t)BB * LL * 512 * 2;
    p.a0_seq  = (float*)(base + off);      off += (size_t)BB * AA * UU * 4;
    p.d0_seq  = (float*)(base + off);      off += (size_t)BB * DQN * UU * 4;
    p.s0_seq  = (float*)(base + off);      off += (size_t)BB * SS * UU * 4;
    p.H       = (float*)(base + off);      off += (size_t)(TT + 1) * BB * UU * 4;
    p.C       = (float*)(base + off);      off += (size_t)(TT + 1) * BB * UU * 4;
    p.zxA     = (uint2*)(base + off);      off += (size_t)BB * LL * UU * 8;
    p.zxB     = (uint2*)(base + off);      off += (size_t)BB * LL * UU * 8;
    p.zxC     = (uint2*)(base + off);      off += (size_t)BB * AA * UU * 8;
    p.zxD     = (uint2*)(base + off);      off += (size_t)BB * DQN * UU * 8;
    p.zxS     = (uint2*)(base + off);      off += (size_t)BB * SS * UU * 8;
    p.pkf     = (float4*)(base + off);     off += (size_t)PK_ROWS_B * 256 * 16;
    const size_t planB_size = off;
    p.zxT     = (float4*)(base + off);     off += (size_t)BB * TT * UU * 16;
    const size_t planC_size = off;

    if (ws_size >= planC_size) {
        // ---- Plan C: tree-zx + XCD-pinned chains ----
        detect_kernel<<<1, 64, 0, stream>>>((const uint_t*)d_in[14], p.flag);
        pack_h_kernel<<<dim3(PK_ROWS_B), dim3(256), 0, stream>>>(p);
        embed_kernel<<<dim3(BB * TT + BB * LL + BB * DQN), dim3(256), 0, stream>>>(p);
        xpre0_kernel<<<dim3(960), dim3(256), 0, stream>>>(p);   // + tree-zx blocks
        p1c_kernel<<<dim3(512), dim3(256), 0, stream>>>(p);
        xpre1_kernel<<<dim3(832), dim3(256), 0, stream>>>(p);
        p2c_kernel<<<dim3(512), dim3(256), 0, stream>>>(p);
        xpre2_kernel<<<dim3(128), dim3(256), 0, stream>>>(p);
        p3_kernel<<<dim3(BB), dim3(256), 0, stream>>>(p);
        final_kernel<<<dim3(BB), dim3(256), 0, stream>>>(p, d_out);
        return;
    }

    if (ws_size >= planB_size) {
        // ---- Plan B: exact round-4 pipeline ----
        p.zxT = (float4*)base;  // unused
        detect_kernel<<<1, 64, 0, stream>>>((const uint_t*)d_in[14], p.flag);
        pack_h_kernel<<<dim3(PK_ROWS_B), dim3(256), 0, stream>>>(p);
        embed_kernel<<<dim3(BB * TT + BB * LL + BB * DQN), dim3(256), 0, stream>>>(p);
        xpre0_kernel<<<dim3(704), dim3(256), 0, stream>>>(p);   // no tree-zx blocks
        p1b_kernel<<<dim3(5 * BB), dim3(256), 0, stream>>>(p);
        xpre1_kernel<<<dim3(832), dim3(256), 0, stream>>>(p);
        p2b_kernel<<<dim3(5 * BB), dim3(256), 0, stream>>>(p);
        xpre2_kernel<<<dim3(128), dim3(256), 0, stream>>>(p);
        p3_kernel<<<dim3(BB), dim3(256), 0, stream>>>(p);
        final_kernel<<<dim3(BB), dim3(256), 0, stream>>>(p, d_out);
        return;
    }

    // ---- Fallback: round-2 layout (~62 MiB) ----
    off = 0;
    p.flag = (int*)(base + off);           off += 16;
    p.stack_h   = (float*)(base + off);    off += (size_t)BB * UU * 4;
    p.fw1_h     = (float*)(base + off);    off += (size_t)BB * UU * 4;
    p.fw_top    = (float*)(base + off);    off += (size_t)BB * UU * 4;
    p.bw_top    = (float*)(base + off);    off += (size_t)BB * UU * 4;
    p.bw_bottom = (float*)(base + off);    off += (size_t)BB * UU * 4;
    p.act_h     = (float*)(base + off);    off += (size_t)BB * UU * 4;
    p.dq_h      = (float*)(base + off);    off += (size_t)BB * UU * 4;
    p.tree_e  = (float*)(base + off);      off += (size_t)BB * TT * UU * 4;
    p.token_e = (ushort_t*)(base + off);   off += (size_t)BB * LL * UU * 2;
    p.deque_e = (ushort_t*)(base + off);   off += (size_t)BB * DQN * UU * 2;
    p.x1      = (ushort_t*)(base + off);   off += (size_t)BB * LL * 512 * 2;
    p.H       = (float*)(base + off);      off += (size_t)(TT + 1) * BB * UU * 4;
    p.C       = (float*)(base + off);      off += (size_t)(TT + 1) * BB * UU * 4;
    p.pkf     = (float4*)(base + off);     off += (size_t)PK_ROWS_FB * 256 * 16;
    p.a0_seq = p.d0_seq = p.s0_seq = (float*)base;
    p.zxA = p.zxB = p.zxC = p.zxD = p.zxS = (uint2*)base;
    p.zxT = (float4*)base;

    if (ws_size < off) {
        sentinel_kernel<<<1, 64, 0, stream>>>(d_out, 7000.f + (float)(ws_size >> 20));
        return;
    }

    detect_kernel<<<1, 64, 0, stream>>>((const uint_t*)d_in[14], p.flag);
    pack_fb_kernel<<<dim3(PK_ROWS_FB), dim3(256), 0, stream>>>(p);
    embed_kernel<<<dim3(BB * TT + BB * LL + BB * DQN), dim3(256), 0, stream>>>(p);
    phase1_fb_kernel<<<dim3(4 * BB), dim3(256), 0, stream>>>(p);
    phase2_fb_kernel<<<dim3(3 * BB), dim3(256), 0, stream>>>(p);
    final_kernel<<<dim3(BB), dim3(256), 0, stream>>>(p, d_out);
}